// Round 1
// baseline (1027.979 us; speedup 1.0000x reference)
//
#include <hip/hip_runtime.h>
#include <hip/hip_fp16.h>
#include <cstdint>
#include <cstddef>

#define U_DIM 2048
#define D_DIM 2048
#define NH 16
#define DH 128
#define DFF 8192
#define EPS_RMS 1e-6f

typedef unsigned short u16;
typedef __attribute__((ext_vector_type(4))) float floatx4;
typedef __attribute__((ext_vector_type(8))) short shortx8;

__device__ __forceinline__ float bf2f(u16 u) {
  union { unsigned int i; float f; } v; v.i = ((unsigned int)u) << 16; return v.f;
}
__device__ __forceinline__ u16 f2bf(float f) {
  union { float f; unsigned int i; } v; v.f = f;
  return (u16)((v.i + 0x7fffu + ((v.i >> 16) & 1u)) >> 16);
}
__device__ __forceinline__ u16 f2h(float f) {
  __half h = __float2half_rn(f);
  union { __half h; u16 u; } c; c.h = h; return c.u;
}
__device__ __forceinline__ float h2f(u16 u) {
  union { __half h; u16 u; } c; c.u = u; return __half2float(c.h);
}

// fp32 -> bf16 bulk convert (n4 = n/4 float4 groups)
__global__ __launch_bounds__(256) void k_f2b(const float* __restrict__ in,
                                             u16* __restrict__ out, int n4) {
  int i = blockIdx.x * 256 + threadIdx.x;
  if (i >= n4) return;
  float4 f = reinterpret_cast<const float4*>(in)[i];
  ushort4 o;
  o.x = f2bf(f.x); o.y = f2bf(f.y); o.z = f2bf(f.z); o.w = f2bf(f.w);
  reinterpret_cast<ushort4*>(out)[i] = o;
}

// rmsnorm: one block per row of [U_DIM, D_DIM], fp32 in -> bf16 out
__global__ __launch_bounds__(256) void k_rmsnorm(const float* __restrict__ x,
                                                 const float* __restrict__ w,
                                                 u16* __restrict__ out) {
  const int row = blockIdx.x;
  const int t = threadIdx.x;
  const float4* xr = reinterpret_cast<const float4*>(x + (size_t)row * D_DIM);
  float4 a0 = xr[t], a1 = xr[t + 256];
  float ss = a0.x*a0.x + a0.y*a0.y + a0.z*a0.z + a0.w*a0.w
           + a1.x*a1.x + a1.y*a1.y + a1.z*a1.z + a1.w*a1.w;
#pragma unroll
  for (int off = 32; off > 0; off >>= 1) ss += __shfl_xor(ss, off);
  __shared__ float red[4];
  if ((t & 63) == 0) red[t >> 6] = ss;
  __syncthreads();
  float tot = red[0] + red[1] + red[2] + red[3];
  float r = rsqrtf(tot / (float)D_DIM + EPS_RMS);
  const float4* wr = reinterpret_cast<const float4*>(w);
  float4 w0 = wr[t], w1 = wr[t + 256];
  ushort4 o0, o1;
  o0.x = f2bf(a0.x * r * w0.x); o0.y = f2bf(a0.y * r * w0.y);
  o0.z = f2bf(a0.z * r * w0.z); o0.w = f2bf(a0.w * r * w0.w);
  o1.x = f2bf(a1.x * r * w1.x); o1.y = f2bf(a1.y * r * w1.y);
  o1.z = f2bf(a1.z * r * w1.z); o1.w = f2bf(a1.w * r * w1.w);
  ushort4* op = reinterpret_cast<ushort4*>(out + (size_t)row * D_DIM);
  op[t] = o0; op[t + 256] = o1;
}

// softmax over rows of [U_DIM] : fp16 scores in -> bf16 probs out (in place)
__global__ __launch_bounds__(256) void k_softmax(u16* __restrict__ S) {
  u16* p = S + ((size_t)blockIdx.y * U_DIM + blockIdx.x) * U_DIM;
  const int t = threadIdx.x;
  ushort4 r0 = reinterpret_cast<ushort4*>(p)[t];
  ushort4 r1 = reinterpret_cast<ushort4*>(p)[t + 256];
  float v[8] = { h2f(r0.x), h2f(r0.y), h2f(r0.z), h2f(r0.w),
                 h2f(r1.x), h2f(r1.y), h2f(r1.z), h2f(r1.w) };
  float m = v[0];
#pragma unroll
  for (int i = 1; i < 8; i++) m = fmaxf(m, v[i]);
#pragma unroll
  for (int off = 32; off > 0; off >>= 1) m = fmaxf(m, __shfl_xor(m, off));
  __shared__ float redm[4], reds[4];
  if ((t & 63) == 0) redm[t >> 6] = m;
  __syncthreads();
  m = fmaxf(fmaxf(redm[0], redm[1]), fmaxf(redm[2], redm[3]));
  float s = 0.f;
#pragma unroll
  for (int i = 0; i < 8; i++) { v[i] = expf(v[i] - m); s += v[i]; }
#pragma unroll
  for (int off = 32; off > 0; off >>= 1) s += __shfl_xor(s, off);
  if ((t & 63) == 0) reds[t >> 6] = s;
  __syncthreads();
  s = reds[0] + reds[1] + reds[2] + reds[3];
  float inv = 1.f / s;
  r0.x = f2bf(v[0]*inv); r0.y = f2bf(v[1]*inv); r0.z = f2bf(v[2]*inv); r0.w = f2bf(v[3]*inv);
  r1.x = f2bf(v[4]*inv); r1.y = f2bf(v[5]*inv); r1.z = f2bf(v[6]*inv); r1.w = f2bf(v[7]*inv);
  reinterpret_cast<ushort4*>(p)[t] = r0;
  reinterpret_cast<ushort4*>(p)[t + 256] = r1;
}

// ---------------- GEMM core: C[128x128] += A[M,K] * B[N,K]^T ----------------
#define BKD 32

__device__ __forceinline__ void async16(u16* lds, const u16* g) {
  __builtin_amdgcn_global_load_lds(
      (__attribute__((address_space(1))) void*)(g),
      (__attribute__((address_space(3))) void*)(lds), 16, 0, 0);
}

__device__ __forceinline__ void gemm_core(
    const u16* __restrict__ A, int lda,
    const u16* __restrict__ B, int ldb,
    int K, int bm, int bn,
    u16* As, u16* Bs, floatx4 acc[4][4]) {
  const int t = threadIdx.x;
  const int wv = t >> 6, lane = t & 63;
  const int wr = wv >> 1, wc = wv & 1;
  // staging: wave wv loads rows [32*wv, 32*wv+32) of the 128-row tile, 16B/lane
  const u16* Ag = A + (size_t)(bm + wv*32 + (lane >> 2)) * lda + (lane & 3) * 8;
  const u16* Bg = B + (size_t)(bn + wv*32 + (lane >> 2)) * ldb + (lane & 3) * 8;
  u16* AsW = As + wv * 1024;  // 32 rows * 32 cols
  u16* BsW = Bs + wv * 1024;
  const int fr = lane & 15, kq = lane >> 4;
  const u16* ApF = As + (wr*64 + fr) * BKD + kq * 8;
  const u16* BpF = Bs + (wc*64 + fr) * BKD + kq * 8;
  for (int k0 = 0; k0 < K; k0 += BKD) {
    async16(AsW,       Ag + k0);
    async16(AsW + 512, Ag + (size_t)16*lda + k0);
    async16(BsW,       Bg + k0);
    async16(BsW + 512, Bg + (size_t)16*ldb + k0);
    __syncthreads();
    shortx8 af[4], bf[4];
#pragma unroll
    for (int i = 0; i < 4; i++) af[i] = *reinterpret_cast<const shortx8*>(ApF + i*16*BKD);
#pragma unroll
    for (int i = 0; i < 4; i++) bf[i] = *reinterpret_cast<const shortx8*>(BpF + i*16*BKD);
#pragma unroll
    for (int mi = 0; mi < 4; mi++)
#pragma unroll
      for (int ni = 0; ni < 4; ni++)
        acc[mi][ni] = __builtin_amdgcn_mfma_f32_16x16x32_bf16(af[mi], bf[ni], acc[mi][ni], 0, 0, 0);
    __syncthreads();
  }
}

#define GEMM_PRELUDE                                              \
  __shared__ u16 As[128*BKD], Bs[128*BKD];                        \
  floatx4 acc[4][4];                                              \
  {                                                               \
    floatx4 zf = {0.f, 0.f, 0.f, 0.f};                            \
    for (int i = 0; i < 4; i++)                                   \
      for (int j = 0; j < 4; j++) acc[i][j] = zf;                 \
  }                                                               \
  const int bm = blockIdx.y * 128, bn = blockIdx.x * 128;

#define EPILOG_SETUP                                              \
  const int lane_ = threadIdx.x & 63;                             \
  const int wv_ = threadIdx.x >> 6;                               \
  const int row0 = (wv_ >> 1) * 64 + ((lane_ >> 4) << 2);         \
  const int col0 = (wv_ & 1) * 64 + (lane_ & 15);

// plain bf16 store
__global__ __launch_bounds__(256) void k_gemm_bf16(
    const u16* __restrict__ A, int lda, const u16* __restrict__ B, int ldb,
    int K, u16* __restrict__ C, int ldc) {
  GEMM_PRELUDE;
  gemm_core(A, lda, B, ldb, K, bm, bn, As, Bs, acc);
  EPILOG_SETUP;
#pragma unroll
  for (int mt = 0; mt < 4; mt++)
#pragma unroll
    for (int i = 0; i < 4; i++) {
      u16* cr = C + (size_t)(bm + row0 + mt*16 + i) * ldc + bn + col0;
#pragma unroll
      for (int nt = 0; nt < 4; nt++) cr[nt*16] = f2bf(acc[mt][nt][i]);
    }
}

// transposed bf16 store: C[col*ldc + row]  (used to build V^T)
__global__ __launch_bounds__(256) void k_gemm_bf16_t(
    const u16* __restrict__ A, int lda, const u16* __restrict__ B, int ldb,
    int K, u16* __restrict__ C, int ldc) {
  GEMM_PRELUDE;
  gemm_core(A, lda, B, ldb, K, bm, bn, As, Bs, acc);
  EPILOG_SETUP;
#pragma unroll
  for (int mt = 0; mt < 4; mt++)
#pragma unroll
    for (int nt = 0; nt < 4; nt++) {
      int col = bn + col0 + nt*16;
      int row = bm + row0 + mt*16;
      ushort4 o;
      o.x = f2bf(acc[mt][nt][0]); o.y = f2bf(acc[mt][nt][1]);
      o.z = f2bf(acc[mt][nt][2]); o.w = f2bf(acc[mt][nt][3]);
      *reinterpret_cast<ushort4*>(C + (size_t)col * ldc + row) = o;
    }
}

// scores: S[z][u][v] = fp16( (q_h . k_h) * scale + adj_bias[u][v] )
__global__ __launch_bounds__(256) void k_gemm_scores(
    const u16* __restrict__ Q, const u16* __restrict__ Km,
    const float* __restrict__ bias, u16* __restrict__ S, int headBase) {
  GEMM_PRELUDE;
  const int gh = headBase + blockIdx.z;
  gemm_core(Q + gh*DH, D_DIM, Km + gh*DH, D_DIM, DH, bm, bn, As, Bs, acc);
  u16* C = S + (size_t)blockIdx.z * U_DIM * U_DIM;
  const float scale = 0.088388347648318447f;  // 1/sqrt(128)
  EPILOG_SETUP;
#pragma unroll
  for (int mt = 0; mt < 4; mt++)
#pragma unroll
    for (int i = 0; i < 4; i++) {
      size_t off = (size_t)(bm + row0 + mt*16 + i) * U_DIM + bn + col0;
#pragma unroll
      for (int nt = 0; nt < 4; nt++)
        C[off + nt*16] = f2h(acc[mt][nt][i] * scale + bias[off + nt*16]);
    }
}

// PV: O[u, gh*DH + d] = attn[z] @ V^T[gh]
__global__ __launch_bounds__(256) void k_gemm_pv(
    const u16* __restrict__ S, const u16* __restrict__ VT,
    u16* __restrict__ O, int headBase) {
  GEMM_PRELUDE;
  const int gh = headBase + blockIdx.z;
  const u16* A = S + (size_t)blockIdx.z * U_DIM * U_DIM;
  const u16* B = VT + (size_t)gh * DH * U_DIM;
  gemm_core(A, U_DIM, B, U_DIM, U_DIM, bm, bn, As, Bs, acc);
  EPILOG_SETUP;
#pragma unroll
  for (int mt = 0; mt < 4; mt++)
#pragma unroll
    for (int i = 0; i < 4; i++) {
      u16* cr = O + (size_t)(bm + row0 + mt*16 + i) * D_DIM + gh*DH + bn + col0;
#pragma unroll
      for (int nt = 0; nt < 4; nt++) cr[nt*16] = f2bf(acc[mt][nt][i]);
    }
}

// residual fp32: Y = X + A@B^T (+ bias[col]) ; X,Y fp32 (may alias elementwise)
__global__ __launch_bounds__(256) void k_gemm_resid(
    const u16* __restrict__ A, int lda, const u16* __restrict__ B, int ldb,
    int K, const float* __restrict__ X, const float* __restrict__ bias,
    float* __restrict__ Y, int ldc) {
  GEMM_PRELUDE;
  gemm_core(A, lda, B, ldb, K, bm, bn, As, Bs, acc);
  EPILOG_SETUP;
#pragma unroll
  for (int mt = 0; mt < 4; mt++)
#pragma unroll
    for (int i = 0; i < 4; i++) {
      size_t off = (size_t)(bm + row0 + mt*16 + i) * ldc + bn + col0;
#pragma unroll
      for (int nt = 0; nt < 4; nt++) {
        float bv = bias ? bias[bn + col0 + nt*16] : 0.f;
        Y[off + nt*16] = X[off + nt*16] + acc[mt][nt][i] + bv;
      }
    }
}

// gelu(A@B^T + bias) -> bf16
__global__ __launch_bounds__(256) void k_gemm_gelu(
    const u16* __restrict__ A, int lda, const u16* __restrict__ B, int ldb,
    int K, const float* __restrict__ bias, u16* __restrict__ C, int ldc) {
  GEMM_PRELUDE;
  gemm_core(A, lda, B, ldb, K, bm, bn, As, Bs, acc);
  EPILOG_SETUP;
#pragma unroll
  for (int mt = 0; mt < 4; mt++)
#pragma unroll
    for (int i = 0; i < 4; i++) {
      size_t off = (size_t)(bm + row0 + mt*16 + i) * ldc + bn + col0;
#pragma unroll
      for (int nt = 0; nt < 4; nt++) {
        float v = acc[mt][nt][i] + bias[bn + col0 + nt*16];
        C[off + nt*16] = f2bf(0.5f * v * (1.f + erff(v * 0.70710678118654752f)));
      }
    }
}

// Workspace layout (peak ~104 MB):
//  0MB: wq_b(8) wk_b(8) wv_b(8) wo_b(8)     [later: ffb 32MB]
// 32MB: hb(8 -- h then h2)
// 40MB: qb(8) kb(8) vtb(8) aob(8)           [later: w_down_b 32MB]
// 72MB: scores chunk (4 heads x 8MB = 32MB) [later: w_up_b 32MB]
extern "C" void kernel_launch(void* const* d_in, const int* in_sizes, int n_in,
                              void* d_out, int out_size, void* d_ws, size_t ws_size,
                              hipStream_t stream) {
  (void)in_sizes; (void)n_in; (void)out_size; (void)ws_size;
  const float* x      = (const float*)d_in[0];
  const float* adj    = (const float*)d_in[1];
  const float* n1w    = (const float*)d_in[2];
  const float* n2w    = (const float*)d_in[3];
  const float* wq     = (const float*)d_in[4];
  const float* wk     = (const float*)d_in[5];
  const float* wv     = (const float*)d_in[6];
  const float* wo     = (const float*)d_in[7];
  const float* w_up   = (const float*)d_in[8];
  const float* b_up   = (const float*)d_in[9];
  const float* w_down = (const float*)d_in[10];
  const float* b_down = (const float*)d_in[11];
  float* out = (float*)d_out;
  char* ws = (char*)d_ws;
  const size_t MB = 1u << 20;
  u16* wqb = (u16*)(ws + 0*MB);
  u16* wkb = (u16*)(ws + 8*MB);
  u16* wvb = (u16*)(ws + 16*MB);
  u16* wob = (u16*)(ws + 24*MB);
  u16* hb  = (u16*)(ws + 32*MB);
  u16* qb  = (u16*)(ws + 40*MB);
  u16* kb  = (u16*)(ws + 48*MB);
  u16* vtb = (u16*)(ws + 56*MB);
  u16* aob = (u16*)(ws + 64*MB);
  u16* scb = (u16*)(ws + 72*MB);
  u16* wub = (u16*)(ws + 72*MB);   // after attention done
  u16* wdb = (u16*)(ws + 40*MB);   // after out-proj done
  u16* ffb = (u16*)(ws + 0*MB);    // after out-proj done

  dim3 blk(256);
  const int n4d = (D_DIM * D_DIM) / 4;
  const int n4f = (DFF * D_DIM) / 4;
  k_f2b<<<(n4d + 255) / 256, blk, 0, stream>>>(wq, wqb, n4d);
  k_f2b<<<(n4d + 255) / 256, blk, 0, stream>>>(wk, wkb, n4d);
  k_f2b<<<(n4d + 255) / 256, blk, 0, stream>>>(wv, wvb, n4d);
  k_f2b<<<(n4d + 255) / 256, blk, 0, stream>>>(wo, wob, n4d);
  k_rmsnorm<<<U_DIM, blk, 0, stream>>>(x, n1w, hb);

  dim3 g16(16, 16);
  k_gemm_bf16  <<<g16, blk, 0, stream>>>(hb, D_DIM, wqb, D_DIM, D_DIM, qb, D_DIM);
  k_gemm_bf16  <<<g16, blk, 0, stream>>>(hb, D_DIM, wkb, D_DIM, D_DIM, kb, D_DIM);
  k_gemm_bf16_t<<<g16, blk, 0, stream>>>(hb, D_DIM, wvb, D_DIM, D_DIM, vtb, U_DIM);

  for (int c = 0; c < 4; c++) {
    k_gemm_scores<<<dim3(16, 16, 4), blk, 0, stream>>>(qb, kb, adj, scb, c*4);
    k_softmax    <<<dim3(U_DIM, 4),  blk, 0, stream>>>(scb);
    k_gemm_pv    <<<dim3(1, 16, 4),  blk, 0, stream>>>(scb, vtb, aob, c*4);
  }

  // out-projection + residual (reads aob, wob, x; writes d_out)
  k_gemm_resid<<<g16, blk, 0, stream>>>(aob, D_DIM, wob, D_DIM, D_DIM, x, nullptr, out, D_DIM);

  // FFN (converts overlay dead regions only after their last readers above)
  k_f2b<<<(n4f + 255) / 256, blk, 0, stream>>>(w_up, wub, n4f);
  k_f2b<<<(n4f + 255) / 256, blk, 0, stream>>>(w_down, wdb, n4f);
  k_rmsnorm<<<U_DIM, blk, 0, stream>>>(out, n2w, hb);
  k_gemm_gelu <<<dim3(64, 16), blk, 0, stream>>>(hb, D_DIM, wub, D_DIM, D_DIM, b_up, ffb, DFF);
  k_gemm_resid<<<g16, blk, 0, stream>>>(ffb, DFF, wdb, DFF, DFF, out, b_down, out, D_DIM);
}

// Round 2
// 912.346 us; speedup vs baseline: 1.1267x; 1.1267x over previous
//
#include <hip/hip_runtime.h>
#include <hip/hip_fp16.h>
#include <cstdint>
#include <cstddef>

#define U_DIM 2048
#define D_DIM 2048
#define NH 16
#define DH 128
#define DFF 8192
#define EPS_RMS 1e-6f

typedef unsigned short u16;
typedef __attribute__((ext_vector_type(4))) float floatx4;
typedef __attribute__((ext_vector_type(8))) short shortx8;

__device__ __forceinline__ u16 f2bf(float f) {
  union { float f; unsigned int i; } v; v.f = f;
  return (u16)((v.i + 0x7fffu + ((v.i >> 16) & 1u)) >> 16);
}
__device__ __forceinline__ u16 f2h(float f) {
  __half h = __float2half_rn(f);
  union { __half h; u16 u; } c; c.h = h; return c.u;
}
__device__ __forceinline__ float h2f(u16 u) {
  union { __half h; u16 u; } c; c.u = u; return __half2float(c.h);
}

// fp32 -> bf16 bulk convert (n4 = n/4 float4 groups)
__global__ __launch_bounds__(256) void k_f2b(const float* __restrict__ in,
                                             u16* __restrict__ out, int n4) {
  int i = blockIdx.x * 256 + threadIdx.x;
  if (i >= n4) return;
  float4 f = reinterpret_cast<const float4*>(in)[i];
  ushort4 o;
  o.x = f2bf(f.x); o.y = f2bf(f.y); o.z = f2bf(f.z); o.w = f2bf(f.w);
  reinterpret_cast<ushort4*>(out)[i] = o;
}

// rmsnorm: one block per row of [U_DIM, D_DIM], fp32 in -> bf16 out
__global__ __launch_bounds__(256) void k_rmsnorm(const float* __restrict__ x,
                                                 const float* __restrict__ w,
                                                 u16* __restrict__ out) {
  const int row = blockIdx.x;
  const int t = threadIdx.x;
  const float4* xr = reinterpret_cast<const float4*>(x + (size_t)row * D_DIM);
  float4 a0 = xr[t], a1 = xr[t + 256];
  float ss = a0.x*a0.x + a0.y*a0.y + a0.z*a0.z + a0.w*a0.w
           + a1.x*a1.x + a1.y*a1.y + a1.z*a1.z + a1.w*a1.w;
#pragma unroll
  for (int off = 32; off > 0; off >>= 1) ss += __shfl_xor(ss, off);
  __shared__ float red[4];
  if ((t & 63) == 0) red[t >> 6] = ss;
  __syncthreads();
  float tot = red[0] + red[1] + red[2] + red[3];
  float r = rsqrtf(tot / (float)D_DIM + EPS_RMS);
  const float4* wr = reinterpret_cast<const float4*>(w);
  float4 w0 = wr[t], w1 = wr[t + 256];
  ushort4 o0, o1;
  o0.x = f2bf(a0.x * r * w0.x); o0.y = f2bf(a0.y * r * w0.y);
  o0.z = f2bf(a0.z * r * w0.z); o0.w = f2bf(a0.w * r * w0.w);
  o1.x = f2bf(a1.x * r * w1.x); o1.y = f2bf(a1.y * r * w1.y);
  o1.z = f2bf(a1.z * r * w1.z); o1.w = f2bf(a1.w * r * w1.w);
  ushort4* op = reinterpret_cast<ushort4*>(out + (size_t)row * D_DIM);
  op[t] = o0; op[t + 256] = o1;
}

// softmax over rows of [U_DIM] : fp16 scores in -> bf16 probs out (in place)
__global__ __launch_bounds__(256) void k_softmax(u16* __restrict__ S) {
  u16* p = S + ((size_t)blockIdx.y * U_DIM + blockIdx.x) * U_DIM;
  const int t = threadIdx.x;
  ushort4 r0 = reinterpret_cast<ushort4*>(p)[t];
  ushort4 r1 = reinterpret_cast<ushort4*>(p)[t + 256];
  float v[8] = { h2f(r0.x), h2f(r0.y), h2f(r0.z), h2f(r0.w),
                 h2f(r1.x), h2f(r1.y), h2f(r1.z), h2f(r1.w) };
  float m = v[0];
#pragma unroll
  for (int i = 1; i < 8; i++) m = fmaxf(m, v[i]);
#pragma unroll
  for (int off = 32; off > 0; off >>= 1) m = fmaxf(m, __shfl_xor(m, off));
  __shared__ float redm[4], reds[4];
  if ((t & 63) == 0) redm[t >> 6] = m;
  __syncthreads();
  m = fmaxf(fmaxf(redm[0], redm[1]), fmaxf(redm[2], redm[3]));
  float s = 0.f;
#pragma unroll
  for (int i = 0; i < 8; i++) { v[i] = expf(v[i] - m); s += v[i]; }
#pragma unroll
  for (int off = 32; off > 0; off >>= 1) s += __shfl_xor(s, off);
  if ((t & 63) == 0) reds[t >> 6] = s;
  __syncthreads();
  s = reds[0] + reds[1] + reds[2] + reds[3];
  float inv = 1.f / s;
  r0.x = f2bf(v[0]*inv); r0.y = f2bf(v[1]*inv); r0.z = f2bf(v[2]*inv); r0.w = f2bf(v[3]*inv);
  r1.x = f2bf(v[4]*inv); r1.y = f2bf(v[5]*inv); r1.z = f2bf(v[6]*inv); r1.w = f2bf(v[7]*inv);
  reinterpret_cast<ushort4*>(p)[t] = r0;
  reinterpret_cast<ushort4*>(p)[t + 256] = r1;
}

// ---------------- GEMM core: C[128x128] += A[M,K] * B[N,K]^T ----------------
#define BKD 32

__device__ __forceinline__ void async16(u16* lds, const u16* g) {
  __builtin_amdgcn_global_load_lds(
      (__attribute__((address_space(1))) void*)(g),
      (__attribute__((address_space(3))) void*)(lds), 16, 0, 0);
}

__device__ __forceinline__ void gemm_core(
    const u16* __restrict__ A, int lda,
    const u16* __restrict__ B, int ldb,
    int K, int bm, int bn,
    u16* As, u16* Bs, floatx4 acc[4][4]) {
  const int t = threadIdx.x;
  const int wv = t >> 6, lane = t & 63;
  const int wr = wv >> 1, wc = wv & 1;
  const u16* Ag = A + (size_t)(bm + wv*32 + (lane >> 2)) * lda + (lane & 3) * 8;
  const u16* Bg = B + (size_t)(bn + wv*32 + (lane >> 2)) * ldb + (lane & 3) * 8;
  u16* AsW = As + wv * 1024;
  u16* BsW = Bs + wv * 1024;
  const int fr = lane & 15, kq = lane >> 4;
  const u16* ApF = As + (wr*64 + fr) * BKD + kq * 8;
  const u16* BpF = Bs + (wc*64 + fr) * BKD + kq * 8;
  for (int k0 = 0; k0 < K; k0 += BKD) {
    async16(AsW,       Ag + k0);
    async16(AsW + 512, Ag + (size_t)16*lda + k0);
    async16(BsW,       Bg + k0);
    async16(BsW + 512, Bg + (size_t)16*ldb + k0);
    __syncthreads();
    shortx8 af[4], bf[4];
#pragma unroll
    for (int i = 0; i < 4; i++) af[i] = *reinterpret_cast<const shortx8*>(ApF + i*16*BKD);
#pragma unroll
    for (int i = 0; i < 4; i++) bf[i] = *reinterpret_cast<const shortx8*>(BpF + i*16*BKD);
#pragma unroll
    for (int mi = 0; mi < 4; mi++)
#pragma unroll
      for (int ni = 0; ni < 4; ni++)
        acc[mi][ni] = __builtin_amdgcn_mfma_f32_16x16x32_bf16(af[mi], bf[ni], acc[mi][ni], 0, 0, 0);
    __syncthreads();
  }
}

#define GEMM_PRELUDE                                              \
  __shared__ u16 As[128*BKD], Bs[128*BKD];                        \
  floatx4 acc[4][4];                                              \
  {                                                               \
    floatx4 zf = {0.f, 0.f, 0.f, 0.f};                            \
    for (int i = 0; i < 4; i++)                                   \
      for (int j = 0; j < 4; j++) acc[i][j] = zf;                 \
  }                                                               \
  const int bm = blockIdx.y * 128, bn = blockIdx.x * 128;

#define EPILOG_SETUP                                              \
  const int lane_ = threadIdx.x & 63;                             \
  const int wv_ = threadIdx.x >> 6;                               \
  const int row0 = (wv_ >> 1) * 64 + ((lane_ >> 4) << 2);         \
  const int col0 = (wv_ & 1) * 64 + (lane_ & 15);

// fused QKV: B = [wq; wk; wv] (6144 x 2048). Q,K stored [U,D]; V stored
// transposed as V^T [D, U] (per-head contiguous: row gh*DH+d is V[:,d] of head gh).
__global__ __launch_bounds__(256) void k_gemm_qkv(
    const u16* __restrict__ A, const u16* __restrict__ B,
    u16* __restrict__ Q, u16* __restrict__ Ko, u16* __restrict__ VT) {
  GEMM_PRELUDE;
  gemm_core(A, D_DIM, B, D_DIM, D_DIM, bm, bn, As, Bs, acc);
  EPILOG_SETUP;
  if (bn < 4096) {  // Q or K, normal store
    u16* C = (bn < 2048) ? Q : Ko;
    const int cb = (bn < 2048) ? bn : bn - 2048;
#pragma unroll
    for (int mt = 0; mt < 4; mt++)
#pragma unroll
      for (int i = 0; i < 4; i++) {
        u16* cr = C + (size_t)(bm + row0 + mt*16 + i) * D_DIM + cb + col0;
#pragma unroll
        for (int nt = 0; nt < 4; nt++) cr[nt*16] = f2bf(acc[mt][nt][i]);
      }
  } else {  // V, transposed store
    const int cb = bn - 4096;
#pragma unroll
    for (int mt = 0; mt < 4; mt++)
#pragma unroll
      for (int nt = 0; nt < 4; nt++) {
        int col = cb + col0 + nt*16;
        int row = bm + row0 + mt*16;
        ushort4 o;
        o.x = f2bf(acc[mt][nt][0]); o.y = f2bf(acc[mt][nt][1]);
        o.z = f2bf(acc[mt][nt][2]); o.w = f2bf(acc[mt][nt][3]);
        *reinterpret_cast<ushort4*>(VT + (size_t)col * U_DIM + row) = o;
      }
  }
}

// scores: S[z][u][v] = fp16( (q_h . k_h) * scale + adj_bias[u][v] )
__global__ __launch_bounds__(256) void k_gemm_scores(
    const u16* __restrict__ Q, const u16* __restrict__ Km,
    const float* __restrict__ bias, u16* __restrict__ S, int headBase) {
  GEMM_PRELUDE;
  const int gh = headBase + blockIdx.z;
  gemm_core(Q + gh*DH, D_DIM, Km + gh*DH, D_DIM, DH, bm, bn, As, Bs, acc);
  u16* C = S + (size_t)blockIdx.z * U_DIM * U_DIM;
  const float scale = 0.088388347648318447f;  // 1/sqrt(128)
  EPILOG_SETUP;
#pragma unroll
  for (int mt = 0; mt < 4; mt++)
#pragma unroll
    for (int i = 0; i < 4; i++) {
      size_t off = (size_t)(bm + row0 + mt*16 + i) * U_DIM + bn + col0;
#pragma unroll
      for (int nt = 0; nt < 4; nt++)
        C[off + nt*16] = f2h(acc[mt][nt][i] * scale + bias[off + nt*16]);
    }
}

// PV split-K: grid (ksplit=4, rowtile=16, head=4); atomicAdd fp32 into PO[U,D]
__global__ __launch_bounds__(256) void k_gemm_pv_splitk(
    const u16* __restrict__ S, const u16* __restrict__ VT,
    float* __restrict__ PO, int headBase) {
  __shared__ u16 As[128*BKD], Bs[128*BKD];
  floatx4 acc[4][4];
  { floatx4 zf = {0.f,0.f,0.f,0.f};
    for (int i = 0; i < 4; i++) for (int j = 0; j < 4; j++) acc[i][j] = zf; }
  const int bm = blockIdx.y * 128, bn = 0;
  const int gh = headBase + blockIdx.z;
  const int Kc = U_DIM / 4;  // 512
  const int koff = blockIdx.x * Kc;
  const u16* A = S + (size_t)blockIdx.z * U_DIM * U_DIM + koff;
  const u16* B = VT + (size_t)gh * DH * U_DIM + koff;
  gemm_core(A, U_DIM, B, U_DIM, Kc, bm, bn, As, Bs, acc);
  EPILOG_SETUP;
#pragma unroll
  for (int mt = 0; mt < 4; mt++)
#pragma unroll
    for (int i = 0; i < 4; i++) {
      float* cr = PO + (size_t)(bm + row0 + mt*16 + i) * D_DIM + gh*DH + col0;
#pragma unroll
      for (int nt = 0; nt < 4; nt++) atomicAdd(&cr[nt*16], acc[mt][nt][i]);
    }
}

// split-K GEMM: atomicAdd fp32 into C (+ bias[col] once, from z==0 chunk)
__global__ __launch_bounds__(256) void k_gemm_splitk(
    const u16* __restrict__ A, int lda, const u16* __restrict__ B, int ldb,
    int Kc, const float* __restrict__ bias, float* __restrict__ C, int ldc) {
  GEMM_PRELUDE;
  const int koff = blockIdx.z * Kc;
  gemm_core(A + koff, lda, B + koff, ldb, Kc, bm, bn, As, Bs, acc);
  EPILOG_SETUP;
  const bool addb = (bias != nullptr) && (blockIdx.z == 0);
#pragma unroll
  for (int mt = 0; mt < 4; mt++)
#pragma unroll
    for (int i = 0; i < 4; i++) {
      float* cr = C + (size_t)(bm + row0 + mt*16 + i) * ldc + bn + col0;
#pragma unroll
      for (int nt = 0; nt < 4; nt++) {
        float v = acc[mt][nt][i];
        if (addb) v += bias[bn + col0 + nt*16];
        atomicAdd(&cr[nt*16], v);
      }
    }
}

// gelu(A@B^T + bias) -> bf16
__global__ __launch_bounds__(256) void k_gemm_gelu(
    const u16* __restrict__ A, int lda, const u16* __restrict__ B, int ldb,
    int K, const float* __restrict__ bias, u16* __restrict__ C, int ldc) {
  GEMM_PRELUDE;
  gemm_core(A, lda, B, ldb, K, bm, bn, As, Bs, acc);
  EPILOG_SETUP;
#pragma unroll
  for (int mt = 0; mt < 4; mt++)
#pragma unroll
    for (int i = 0; i < 4; i++) {
      size_t off = (size_t)(bm + row0 + mt*16 + i) * ldc + bn + col0;
#pragma unroll
      for (int nt = 0; nt < 4; nt++) {
        float v = acc[mt][nt][i] + bias[bn + col0 + nt*16];
        C[off + nt*16] = f2bf(0.5f * v * (1.f + erff(v * 0.70710678118654752f)));
      }
    }
}

// Workspace layout (peak 104 MB), phase overlays:
//   0- 8 : wob                      | FFN: wub (0-32)
//   8-16 : qb                       |
//  16-24 : kb                       |
//  24-32 : vtb                      |
//  32-48 : hb(32-40) then paob fp32 | FFN: wdb (32-64)
//  48-80 : scb (4-head fp16 chunk); aob bf16 at 48-56 after attention
//  64-72 :                          | FFN: h2
//  72-104:                          | FFN: ffb
//  80-104: wqkv (QKV phase only)
extern "C" void kernel_launch(void* const* d_in, const int* in_sizes, int n_in,
                              void* d_out, int out_size, void* d_ws, size_t ws_size,
                              hipStream_t stream) {
  (void)in_sizes; (void)n_in; (void)out_size; (void)ws_size;
  const float* x      = (const float*)d_in[0];
  const float* adj    = (const float*)d_in[1];
  const float* n1w    = (const float*)d_in[2];
  const float* n2w    = (const float*)d_in[3];
  const float* wq     = (const float*)d_in[4];
  const float* wk     = (const float*)d_in[5];
  const float* wv     = (const float*)d_in[6];
  const float* wo     = (const float*)d_in[7];
  const float* w_up   = (const float*)d_in[8];
  const float* b_up   = (const float*)d_in[9];
  const float* w_down = (const float*)d_in[10];
  const float* b_down = (const float*)d_in[11];
  float* out = (float*)d_out;
  char* ws = (char*)d_ws;
  const size_t MB = 1u << 20;
  u16*   wob  = (u16*)(ws + 0*MB);
  u16*   qb   = (u16*)(ws + 8*MB);
  u16*   kb   = (u16*)(ws + 16*MB);
  u16*   vtb  = (u16*)(ws + 24*MB);
  u16*   hb   = (u16*)(ws + 32*MB);
  float* paob = (float*)(ws + 32*MB);
  u16*   scb  = (u16*)(ws + 48*MB);
  u16*   aob  = (u16*)(ws + 48*MB);
  u16*   wqkv = (u16*)(ws + 80*MB);
  u16*   wub  = (u16*)(ws + 0*MB);
  u16*   wdb  = (u16*)(ws + 32*MB);
  u16*   h2b  = (u16*)(ws + 64*MB);
  u16*   ffb  = (u16*)(ws + 72*MB);

  dim3 blk(256);
  const int n4d = (D_DIM * D_DIM) / 4;
  const int n4f = (DFF * D_DIM) / 4;

  // phase 1: weight conversion + norm1
  k_f2b<<<(n4d + 255) / 256, blk, 0, stream>>>(wq, wqkv, n4d);
  k_f2b<<<(n4d + 255) / 256, blk, 0, stream>>>(wk, wqkv + (size_t)D_DIM*D_DIM, n4d);
  k_f2b<<<(n4d + 255) / 256, blk, 0, stream>>>(wv, wqkv + 2*(size_t)D_DIM*D_DIM, n4d);
  k_f2b<<<(n4d + 255) / 256, blk, 0, stream>>>(wo, wob, n4d);
  k_rmsnorm<<<U_DIM, blk, 0, stream>>>(x, n1w, hb);

  // phase 2: fused QKV (768 blocks)
  k_gemm_qkv<<<dim3(48, 16), blk, 0, stream>>>(hb, wqkv, qb, kb, vtb);

  // phase 3: attention, 4 heads per chunk; PV split-K4 accumulates into paob
  hipMemsetAsync(paob, 0, (size_t)U_DIM * D_DIM * sizeof(float), stream);
  for (int c = 0; c < 4; c++) {
    k_gemm_scores  <<<dim3(16, 16, 4), blk, 0, stream>>>(qb, kb, adj, scb, c*4);
    k_softmax      <<<dim3(U_DIM, 4),  blk, 0, stream>>>(scb);
    k_gemm_pv_splitk<<<dim3(4, 16, 4), blk, 0, stream>>>(scb, vtb, paob, c*4);
  }
  k_f2b<<<(n4d + 255) / 256, blk, 0, stream>>>(paob, aob, n4d);

  // phase 4: out-projection + residual, split-K2 atomic onto out = x
  hipMemcpyAsync(out, x, (size_t)U_DIM * D_DIM * sizeof(float),
                 hipMemcpyDeviceToDevice, stream);
  k_gemm_splitk<<<dim3(16, 16, 2), blk, 0, stream>>>(aob, D_DIM, wob, D_DIM,
                                                     D_DIM/2, nullptr, out, D_DIM);

  // phase 5: FFN
  k_f2b<<<(n4f + 255) / 256, blk, 0, stream>>>(w_up, wub, n4f);
  k_f2b<<<(n4f + 255) / 256, blk, 0, stream>>>(w_down, wdb, n4f);
  k_rmsnorm<<<U_DIM, blk, 0, stream>>>(out, n2w, h2b);
  k_gemm_gelu<<<dim3(64, 16), blk, 0, stream>>>(h2b, D_DIM, wub, D_DIM, D_DIM,
                                                b_up, ffb, DFF);
  k_gemm_splitk<<<dim3(16, 16, 4), blk, 0, stream>>>(ffb, DFF, wdb, DFF,
                                                     DFF/4, b_down, out, D_DIM);
}

// Round 3
// 808.900 us; speedup vs baseline: 1.2708x; 1.1279x over previous
//
#include <hip/hip_runtime.h>
#include <hip/hip_fp16.h>
#include <cstdint>
#include <cstddef>

#define U_DIM 2048
#define D_DIM 2048
#define NH 16
#define DH 128
#define DFF 8192
#define EPS_RMS 1e-6f

typedef unsigned short u16;
typedef __attribute__((ext_vector_type(4))) float floatx4;
typedef __attribute__((ext_vector_type(8))) short shortx8;

__device__ __forceinline__ float bf2f(u16 u) {
  union { unsigned int i; float f; } v; v.i = ((unsigned int)u) << 16; return v.f;
}
__device__ __forceinline__ u16 f2bf(float f) {
  union { float f; unsigned int i; } v; v.f = f;
  return (u16)((v.i + 0x7fffu + ((v.i >> 16) & 1u)) >> 16);
}
__device__ __forceinline__ u16 f2h(float f) {
  __half h = __float2half_rn(f);
  union { __half h; u16 u; } c; c.h = h; return c.u;
}
__device__ __forceinline__ float h2f(u16 u) {
  union { __half h; u16 u; } c; c.u = u; return __half2float(c.h);
}

// fp32 -> bf16 bulk convert (n4 = n/4 float4 groups)
__global__ __launch_bounds__(256) void k_f2b(const float* __restrict__ in,
                                             u16* __restrict__ out, int n4) {
  int i = blockIdx.x * 256 + threadIdx.x;
  if (i >= n4) return;
  float4 f = reinterpret_cast<const float4*>(in)[i];
  ushort4 o;
  o.x = f2bf(f.x); o.y = f2bf(f.y); o.z = f2bf(f.z); o.w = f2bf(f.w);
  reinterpret_cast<ushort4*>(out)[i] = o;
}

// out4 = X4 + sum of 4 bf16 partials (+ bias[col]); fp32 out
__global__ __launch_bounds__(256) void k_reduce4(
    const u16* __restrict__ p0, const u16* __restrict__ p1,
    const u16* __restrict__ p2, const u16* __restrict__ p3,
    const float* __restrict__ X, const float* __restrict__ bias,
    float* __restrict__ out, int n4) {
  int i = blockIdx.x * 256 + threadIdx.x;
  if (i >= n4) return;
  ushort4 a = reinterpret_cast<const ushort4*>(p0)[i];
  ushort4 b = reinterpret_cast<const ushort4*>(p1)[i];
  ushort4 c = reinterpret_cast<const ushort4*>(p2)[i];
  ushort4 d = reinterpret_cast<const ushort4*>(p3)[i];
  float4 xv = reinterpret_cast<const float4*>(X)[i];
  float4 r;
  r.x = xv.x + bf2f(a.x) + bf2f(b.x) + bf2f(c.x) + bf2f(d.x);
  r.y = xv.y + bf2f(a.y) + bf2f(b.y) + bf2f(c.y) + bf2f(d.y);
  r.z = xv.z + bf2f(a.z) + bf2f(b.z) + bf2f(c.z) + bf2f(d.z);
  r.w = xv.w + bf2f(a.w) + bf2f(b.w) + bf2f(c.w) + bf2f(d.w);
  if (bias) {
    int col = (i * 4) & (D_DIM - 1);
    float4 bv = *reinterpret_cast<const float4*>(bias + col);
    r.x += bv.x; r.y += bv.y; r.z += bv.z; r.w += bv.w;
  }
  reinterpret_cast<float4*>(out)[i] = r;
}

// bf16 out = sum of 4 bf16 partials
__global__ __launch_bounds__(256) void k_reduce4_bf(
    const u16* __restrict__ p0, const u16* __restrict__ p1,
    const u16* __restrict__ p2, const u16* __restrict__ p3,
    u16* __restrict__ out, int n4) {
  int i = blockIdx.x * 256 + threadIdx.x;
  if (i >= n4) return;
  ushort4 a = reinterpret_cast<const ushort4*>(p0)[i];
  ushort4 b = reinterpret_cast<const ushort4*>(p1)[i];
  ushort4 c = reinterpret_cast<const ushort4*>(p2)[i];
  ushort4 d = reinterpret_cast<const ushort4*>(p3)[i];
  ushort4 o;
  o.x = f2bf(bf2f(a.x) + bf2f(b.x) + bf2f(c.x) + bf2f(d.x));
  o.y = f2bf(bf2f(a.y) + bf2f(b.y) + bf2f(c.y) + bf2f(d.y));
  o.z = f2bf(bf2f(a.z) + bf2f(b.z) + bf2f(c.z) + bf2f(d.z));
  o.w = f2bf(bf2f(a.w) + bf2f(b.w) + bf2f(c.w) + bf2f(d.w));
  reinterpret_cast<ushort4*>(out)[i] = o;
}

// rmsnorm: one block per row of [U_DIM, D_DIM], fp32 in -> bf16 out
__global__ __launch_bounds__(256) void k_rmsnorm(const float* __restrict__ x,
                                                 const float* __restrict__ w,
                                                 u16* __restrict__ out) {
  const int row = blockIdx.x;
  const int t = threadIdx.x;
  const float4* xr = reinterpret_cast<const float4*>(x + (size_t)row * D_DIM);
  float4 a0 = xr[t], a1 = xr[t + 256];
  float ss = a0.x*a0.x + a0.y*a0.y + a0.z*a0.z + a0.w*a0.w
           + a1.x*a1.x + a1.y*a1.y + a1.z*a1.z + a1.w*a1.w;
#pragma unroll
  for (int off = 32; off > 0; off >>= 1) ss += __shfl_xor(ss, off);
  __shared__ float red[4];
  if ((t & 63) == 0) red[t >> 6] = ss;
  __syncthreads();
  float tot = red[0] + red[1] + red[2] + red[3];
  float r = rsqrtf(tot / (float)D_DIM + EPS_RMS);
  const float4* wr = reinterpret_cast<const float4*>(w);
  float4 w0 = wr[t], w1 = wr[t + 256];
  ushort4 o0, o1;
  o0.x = f2bf(a0.x * r * w0.x); o0.y = f2bf(a0.y * r * w0.y);
  o0.z = f2bf(a0.z * r * w0.z); o0.w = f2bf(a0.w * r * w0.w);
  o1.x = f2bf(a1.x * r * w1.x); o1.y = f2bf(a1.y * r * w1.y);
  o1.z = f2bf(a1.z * r * w1.z); o1.w = f2bf(a1.w * r * w1.w);
  ushort4* op = reinterpret_cast<ushort4*>(out + (size_t)row * D_DIM);
  op[t] = o0; op[t + 256] = o1;
}

// softmax over rows of [U_DIM] : fp16 scores in -> bf16 probs out (in place)
__global__ __launch_bounds__(256) void k_softmax(u16* __restrict__ S) {
  u16* p = S + ((size_t)blockIdx.y * U_DIM + blockIdx.x) * U_DIM;
  const int t = threadIdx.x;
  ushort4 r0 = reinterpret_cast<ushort4*>(p)[t];
  ushort4 r1 = reinterpret_cast<ushort4*>(p)[t + 256];
  float v[8] = { h2f(r0.x), h2f(r0.y), h2f(r0.z), h2f(r0.w),
                 h2f(r1.x), h2f(r1.y), h2f(r1.z), h2f(r1.w) };
  float m = v[0];
#pragma unroll
  for (int i = 1; i < 8; i++) m = fmaxf(m, v[i]);
#pragma unroll
  for (int off = 32; off > 0; off >>= 1) m = fmaxf(m, __shfl_xor(m, off));
  __shared__ float redm[4], reds[4];
  if ((t & 63) == 0) redm[t >> 6] = m;
  __syncthreads();
  m = fmaxf(fmaxf(redm[0], redm[1]), fmaxf(redm[2], redm[3]));
  float s = 0.f;
#pragma unroll
  for (int i = 0; i < 8; i++) { v[i] = expf(v[i] - m); s += v[i]; }
#pragma unroll
  for (int off = 32; off > 0; off >>= 1) s += __shfl_xor(s, off);
  if ((t & 63) == 0) reds[t >> 6] = s;
  __syncthreads();
  s = reds[0] + reds[1] + reds[2] + reds[3];
  float inv = 1.f / s;
  r0.x = f2bf(v[0]*inv); r0.y = f2bf(v[1]*inv); r0.z = f2bf(v[2]*inv); r0.w = f2bf(v[3]*inv);
  r1.x = f2bf(v[4]*inv); r1.y = f2bf(v[5]*inv); r1.z = f2bf(v[6]*inv); r1.w = f2bf(v[7]*inv);
  reinterpret_cast<ushort4*>(p)[t] = r0;
  reinterpret_cast<ushort4*>(p)[t + 256] = r1;
}

// ---------------- GEMM core: C[128x128] += A[M,K] * B[N,K]^T ----------------
#define BKD 32

__device__ __forceinline__ void async16(u16* lds, const u16* g) {
  __builtin_amdgcn_global_load_lds(
      (__attribute__((address_space(1))) void*)(g),
      (__attribute__((address_space(3))) void*)(lds), 16, 0, 0);
}

__device__ __forceinline__ void gemm_core(
    const u16* __restrict__ A, int lda,
    const u16* __restrict__ B, int ldb,
    int K, int bm, int bn,
    u16* As, u16* Bs, floatx4 acc[4][4]) {
  const int t = threadIdx.x;
  const int wv = t >> 6, lane = t & 63;
  const int wr = wv >> 1, wc = wv & 1;
  const u16* Ag = A + (size_t)(bm + wv*32 + (lane >> 2)) * lda + (lane & 3) * 8;
  const u16* Bg = B + (size_t)(bn + wv*32 + (lane >> 2)) * ldb + (lane & 3) * 8;
  u16* AsW = As + wv * 1024;
  u16* BsW = Bs + wv * 1024;
  const int fr = lane & 15, kq = lane >> 4;
  const u16* ApF = As + (wr*64 + fr) * BKD + kq * 8;
  const u16* BpF = Bs + (wc*64 + fr) * BKD + kq * 8;
  for (int k0 = 0; k0 < K; k0 += BKD) {
    async16(AsW,       Ag + k0);
    async16(AsW + 512, Ag + (size_t)16*lda + k0);
    async16(BsW,       Bg + k0);
    async16(BsW + 512, Bg + (size_t)16*ldb + k0);
    __syncthreads();
    shortx8 af[4], bf[4];
#pragma unroll
    for (int i = 0; i < 4; i++) af[i] = *reinterpret_cast<const shortx8*>(ApF + i*16*BKD);
#pragma unroll
    for (int i = 0; i < 4; i++) bf[i] = *reinterpret_cast<const shortx8*>(BpF + i*16*BKD);
#pragma unroll
    for (int mi = 0; mi < 4; mi++)
#pragma unroll
      for (int ni = 0; ni < 4; ni++)
        acc[mi][ni] = __builtin_amdgcn_mfma_f32_16x16x32_bf16(af[mi], bf[ni], acc[mi][ni], 0, 0, 0);
    __syncthreads();
  }
}

#define GEMM_PRELUDE                                              \
  __shared__ u16 As[128*BKD], Bs[128*BKD];                        \
  floatx4 acc[4][4];                                              \
  {                                                               \
    floatx4 zf = {0.f, 0.f, 0.f, 0.f};                            \
    for (int i = 0; i < 4; i++)                                   \
      for (int j = 0; j < 4; j++) acc[i][j] = zf;                 \
  }                                                               \
  const int bm = blockIdx.y * 128, bn = blockIdx.x * 128;

#define EPILOG_SETUP                                              \
  const int lane_ = threadIdx.x & 63;                             \
  const int wv_ = threadIdx.x >> 6;                               \
  const int row0 = (wv_ >> 1) * 64 + ((lane_ >> 4) << 2);         \
  const int col0 = (wv_ & 1) * 64 + (lane_ & 15);

// fused QKV: B = [wq; wk; wv] (6144 x 2048). Q,K stored [U,D]; V stored
// transposed as V^T [D, U] (per-head contiguous).
__global__ __launch_bounds__(256) void k_gemm_qkv(
    const u16* __restrict__ A, const u16* __restrict__ B,
    u16* __restrict__ Q, u16* __restrict__ Ko, u16* __restrict__ VT) {
  GEMM_PRELUDE;
  gemm_core(A, D_DIM, B, D_DIM, D_DIM, bm, bn, As, Bs, acc);
  EPILOG_SETUP;
  if (bn < 4096) {  // Q or K, normal store
    u16* C = (bn < 2048) ? Q : Ko;
    const int cb = (bn < 2048) ? bn : bn - 2048;
#pragma unroll
    for (int mt = 0; mt < 4; mt++)
#pragma unroll
      for (int i = 0; i < 4; i++) {
        u16* cr = C + (size_t)(bm + row0 + mt*16 + i) * D_DIM + cb + col0;
#pragma unroll
        for (int nt = 0; nt < 4; nt++) cr[nt*16] = f2bf(acc[mt][nt][i]);
      }
  } else {  // V, transposed store
    const int cb = bn - 4096;
#pragma unroll
    for (int mt = 0; mt < 4; mt++)
#pragma unroll
      for (int nt = 0; nt < 4; nt++) {
        int col = cb + col0 + nt*16;
        int row = bm + row0 + mt*16;
        ushort4 o;
        o.x = f2bf(acc[mt][nt][0]); o.y = f2bf(acc[mt][nt][1]);
        o.z = f2bf(acc[mt][nt][2]); o.w = f2bf(acc[mt][nt][3]);
        *reinterpret_cast<ushort4*>(VT + (size_t)col * U_DIM + row) = o;
      }
  }
}

// scores: S[z][u][v] = fp16( (q_h . k_h) * scale + adj_bias[u][v] )
__global__ __launch_bounds__(256) void k_gemm_scores(
    const u16* __restrict__ Q, const u16* __restrict__ Km,
    const float* __restrict__ bias, u16* __restrict__ S, int headBase) {
  GEMM_PRELUDE;
  const int gh = headBase + blockIdx.z;
  gemm_core(Q + gh*DH, D_DIM, Km + gh*DH, D_DIM, DH, bm, bn, As, Bs, acc);
  u16* C = S + (size_t)blockIdx.z * U_DIM * U_DIM;
  const float scale = 0.088388347648318447f;  // 1/sqrt(128)
  EPILOG_SETUP;
#pragma unroll
  for (int mt = 0; mt < 4; mt++)
#pragma unroll
    for (int i = 0; i < 4; i++) {
      size_t off = (size_t)(bm + row0 + mt*16 + i) * U_DIM + bn + col0;
#pragma unroll
      for (int nt = 0; nt < 4; nt++)
        C[off + nt*16] = f2h(acc[mt][nt][i] * scale + bias[off + nt*16]);
    }
}

// PV split-K into 4 bf16 partial buffers. grid (split=4, rowtile=16, head=4).
__global__ __launch_bounds__(256) void k_gemm_pv_part(
    const u16* __restrict__ S, const u16* __restrict__ VT,
    u16* __restrict__ p0, u16* __restrict__ p1,
    u16* __restrict__ p2, u16* __restrict__ p3, int headBase) {
  __shared__ u16 As[128*BKD], Bs[128*BKD];
  floatx4 acc[4][4];
  { floatx4 zf = {0.f,0.f,0.f,0.f};
    for (int i = 0; i < 4; i++) for (int j = 0; j < 4; j++) acc[i][j] = zf; }
  const int bm = blockIdx.y * 128, bn = 0;
  const int gh = headBase + blockIdx.z;
  const int Kc = U_DIM / 4;  // 512
  const int koff = blockIdx.x * Kc;
  const u16* A = S + (size_t)blockIdx.z * U_DIM * U_DIM + koff;
  const u16* B = VT + (size_t)gh * DH * U_DIM + koff;
  gemm_core(A, U_DIM, B, U_DIM, Kc, bm, bn, As, Bs, acc);
  u16* P = (blockIdx.x == 0) ? p0 : (blockIdx.x == 1) ? p1
         : (blockIdx.x == 2) ? p2 : p3;
  EPILOG_SETUP;
#pragma unroll
  for (int mt = 0; mt < 4; mt++)
#pragma unroll
    for (int i = 0; i < 4; i++) {
      u16* cr = P + (size_t)(bm + row0 + mt*16 + i) * D_DIM + gh*DH + col0;
#pragma unroll
      for (int nt = 0; nt < 4; nt++) cr[nt*16] = f2bf(acc[mt][nt][i]);
    }
}

// split-K GEMM into 4 bf16 partial buffers (grid.z = split)
__global__ __launch_bounds__(256) void k_gemm_splitk_part(
    const u16* __restrict__ A, int lda, const u16* __restrict__ B, int ldb,
    int Kc, u16* __restrict__ P, size_t pstride, int ldc) {
  GEMM_PRELUDE;
  const int koff = blockIdx.z * Kc;
  gemm_core(A + koff, lda, B + koff, ldb, Kc, bm, bn, As, Bs, acc);
  u16* Pz = P + (size_t)blockIdx.z * pstride;
  EPILOG_SETUP;
#pragma unroll
  for (int mt = 0; mt < 4; mt++)
#pragma unroll
    for (int i = 0; i < 4; i++) {
      u16* cr = Pz + (size_t)(bm + row0 + mt*16 + i) * ldc + bn + col0;
#pragma unroll
      for (int nt = 0; nt < 4; nt++) cr[nt*16] = f2bf(acc[mt][nt][i]);
    }
}

// gelu(A@B^T + bias) -> bf16
__global__ __launch_bounds__(256) void k_gemm_gelu(
    const u16* __restrict__ A, int lda, const u16* __restrict__ B, int ldb,
    int K, const float* __restrict__ bias, u16* __restrict__ C, int ldc) {
  GEMM_PRELUDE;
  gemm_core(A, lda, B, ldb, K, bm, bn, As, Bs, acc);
  EPILOG_SETUP;
#pragma unroll
  for (int mt = 0; mt < 4; mt++)
#pragma unroll
    for (int i = 0; i < 4; i++) {
      size_t off = (size_t)(bm + row0 + mt*16 + i) * ldc + bn + col0;
#pragma unroll
      for (int nt = 0; nt < 4; nt++) {
        float v = acc[mt][nt][i] + bias[bn + col0 + nt*16];
        C[off + nt*16] = f2bf(0.5f * v * (1.f + erff(v * 0.70710678118654752f)));
      }
    }
}

// Workspace timeline (MB offsets, peak 104):
//  A: wob@0-8  hb@32-40  wqkv@80-104
//  B: qkv gemm -> qb@8-16 kb@16-24 vtb@24-32
//  C: scb@48-80 (fp16, 4 heads); pv partials p0@32-40 p1@80-88 p2@88-96 p3@96-104
//     reduce -> aob@40-48
//  D: out-proj partials op0..3@8,16,24,32; reduce -> out = x + sum
//  E: h2b@0-8  wub@8-40  ffb@40-72  wdb@72-104; down partials dp0..3@8,16,24,32
//     (overlay wub, dead after gelu); reduce -> out += sum + b_down
extern "C" void kernel_launch(void* const* d_in, const int* in_sizes, int n_in,
                              void* d_out, int out_size, void* d_ws, size_t ws_size,
                              hipStream_t stream) {
  (void)in_sizes; (void)n_in; (void)out_size; (void)ws_size;
  const float* x      = (const float*)d_in[0];
  const float* adj    = (const float*)d_in[1];
  const float* n1w    = (const float*)d_in[2];
  const float* n2w    = (const float*)d_in[3];
  const float* wq     = (const float*)d_in[4];
  const float* wk     = (const float*)d_in[5];
  const float* wv     = (const float*)d_in[6];
  const float* wo     = (const float*)d_in[7];
  const float* w_up   = (const float*)d_in[8];
  const float* b_up   = (const float*)d_in[9];
  const float* w_down = (const float*)d_in[10];
  const float* b_down = (const float*)d_in[11];
  float* out = (float*)d_out;
  char* ws = (char*)d_ws;
  const size_t MB = 1u << 20;
  // phase A/B
  u16* wob  = (u16*)(ws + 0*MB);
  u16* qb   = (u16*)(ws + 8*MB);
  u16* kb   = (u16*)(ws + 16*MB);
  u16* vtb  = (u16*)(ws + 24*MB);
  u16* hb   = (u16*)(ws + 32*MB);
  u16* wqkv = (u16*)(ws + 80*MB);
  // phase C
  u16* scb  = (u16*)(ws + 48*MB);
  u16* pv0  = (u16*)(ws + 32*MB);
  u16* pv1  = (u16*)(ws + 80*MB);
  u16* pv2  = (u16*)(ws + 88*MB);
  u16* pv3  = (u16*)(ws + 96*MB);
  u16* aob  = (u16*)(ws + 40*MB);
  // phase D
  u16* opp  = (u16*)(ws + 8*MB);   // 4 x 8MB partials @8,16,24,32
  // phase E
  u16* h2b  = (u16*)(ws + 0*MB);
  u16* wub  = (u16*)(ws + 8*MB);
  u16* ffb  = (u16*)(ws + 40*MB);
  u16* wdb  = (u16*)(ws + 72*MB);
  u16* dpp  = (u16*)(ws + 8*MB);   // 4 x 8MB partials, overlays wub after gelu

  dim3 blk(256);
  const int n4d = (D_DIM * D_DIM) / 4;
  const int n4f = (DFF * D_DIM) / 4;
  const size_t szd = (size_t)D_DIM * D_DIM;  // elements in a [2048,2048] buffer

  // phase A: weight conversion + norm1
  k_f2b<<<(n4d + 255) / 256, blk, 0, stream>>>(wq, wqkv, n4d);
  k_f2b<<<(n4d + 255) / 256, blk, 0, stream>>>(wk, wqkv + szd, n4d);
  k_f2b<<<(n4d + 255) / 256, blk, 0, stream>>>(wv, wqkv + 2*szd, n4d);
  k_f2b<<<(n4d + 255) / 256, blk, 0, stream>>>(wo, wob, n4d);
  k_rmsnorm<<<U_DIM, blk, 0, stream>>>(x, n1w, hb);

  // phase B: fused QKV (768 blocks)
  k_gemm_qkv<<<dim3(48, 16), blk, 0, stream>>>(hb, wqkv, qb, kb, vtb);

  // phase C: attention, 4 heads per chunk; PV split-K4 -> bf16 partials
  for (int c = 0; c < 4; c++) {
    k_gemm_scores<<<dim3(16, 16, 4), blk, 0, stream>>>(qb, kb, adj, scb, c*4);
    k_softmax    <<<dim3(U_DIM, 4),  blk, 0, stream>>>(scb);
    k_gemm_pv_part<<<dim3(4, 16, 4), blk, 0, stream>>>(scb, vtb, pv0, pv1, pv2, pv3, c*4);
  }
  k_reduce4_bf<<<(n4d + 255) / 256, blk, 0, stream>>>(pv0, pv1, pv2, pv3, aob, n4d);

  // phase D: out-projection split-K4 -> partials; reduce adds residual x
  k_gemm_splitk_part<<<dim3(16, 16, 4), blk, 0, stream>>>(
      aob, D_DIM, wob, D_DIM, D_DIM/4, opp, szd, D_DIM);
  k_reduce4<<<(n4d + 255) / 256, blk, 0, stream>>>(
      opp, opp + szd, opp + 2*szd, opp + 3*szd, x, nullptr, out, n4d);

  // phase E: FFN
  k_rmsnorm<<<U_DIM, blk, 0, stream>>>(out, n2w, h2b);
  k_f2b<<<(n4f + 255) / 256, blk, 0, stream>>>(w_up, wub, n4f);
  k_gemm_gelu<<<dim3(64, 16), blk, 0, stream>>>(h2b, D_DIM, wub, D_DIM, D_DIM,
                                                b_up, ffb, DFF);
  k_f2b<<<(n4f + 255) / 256, blk, 0, stream>>>(w_down, wdb, n4f);
  k_gemm_splitk_part<<<dim3(16, 16, 4), blk, 0, stream>>>(
      ffb, DFF, wdb, DFF, DFF/4, dpp, szd, D_DIM);
  k_reduce4<<<(n4d + 255) / 256, blk, 0, stream>>>(
      dpp, dpp + szd, dpp + 2*szd, dpp + 3*szd, out, b_down, out, n4d);
}

// Round 5
// 756.686 us; speedup vs baseline: 1.3585x; 1.0690x over previous
//
#include <hip/hip_runtime.h>
#include <hip/hip_fp16.h>
#include <cstdint>
#include <cstddef>

#define U_DIM 2048
#define D_DIM 2048
#define NH 16
#define DH 128
#define DFF 8192
#define EPS_RMS 1e-6f
#define ATTN_SCALE 0.088388347648318447f

typedef unsigned short u16;
typedef __attribute__((ext_vector_type(4))) float floatx4;
typedef __attribute__((ext_vector_type(8))) short shortx8;

__device__ __forceinline__ float bf2f(u16 u) {
  union { unsigned int i; float f; } v; v.i = ((unsigned int)u) << 16; return v.f;
}
__device__ __forceinline__ u16 f2bf(float f) {
  union { float f; unsigned int i; } v; v.f = f;
  return (u16)((v.i + 0x7fffu + ((v.i >> 16) & 1u)) >> 16);
}
__device__ __forceinline__ u16 f2h(float f) {
  __half h = __float2half_rn(f);
  union { __half h; u16 u; } c; c.h = h; return c.u;
}
__device__ __forceinline__ float h2f(u16 u) {
  union { __half h; u16 u; } c; c.u = u; return __half2float(c.h);
}

// fp32 -> bf16 bulk convert (n4 = n/4 float4 groups)
__global__ __launch_bounds__(256) void k_f2b(const float* __restrict__ in,
                                             u16* __restrict__ out, int n4) {
  int i = blockIdx.x * 256 + threadIdx.x;
  if (i >= n4) return;
  float4 f = reinterpret_cast<const float4*>(in)[i];
  ushort4 o;
  o.x = f2bf(f.x); o.y = f2bf(f.y); o.z = f2bf(f.z); o.w = f2bf(f.w);
  reinterpret_cast<ushort4*>(out)[i] = o;
}

// Permute adj fp32 [U,U] into frag-major fp16 tiles:
// adjp[(qt*16+kt)*16384 + (c16*128 + row)*8 + j] = adj[qt*128+row][kt*128+c16+16*j]
__global__ __launch_bounds__(256) void k_prep_bias(const float* __restrict__ adj,
                                                   u16* __restrict__ adjp) {
  const int tile = blockIdx.x;           // qt*16 + kt
  const int qt = tile >> 4, kt = tile & 15;
  const int t = threadIdx.x;
  const int c16 = t & 15, rblk = t >> 4; // 16 row-groups of 8
  u16* outt = adjp + (size_t)tile * 16384;
#pragma unroll
  for (int rr = 0; rr < 8; rr++) {
    int r = rblk * 8 + rr;
    const float* src = adj + (size_t)(qt * 128 + r) * U_DIM + kt * 128 + c16;
    ushort4 o0, o1;
    o0.x = f2h(src[0]);    o0.y = f2h(src[16]);  o0.z = f2h(src[32]);  o0.w = f2h(src[48]);
    o1.x = f2h(src[64]);   o1.y = f2h(src[80]);  o1.z = f2h(src[96]);  o1.w = f2h(src[112]);
    ushort4* dst = reinterpret_cast<ushort4*>(outt + ((size_t)c16 * 128 + r) * 8);
    dst[0] = o0; dst[1] = o1;
  }
}

// out4 = X4 + sum of 4 bf16 partials (+ bias[col]); fp32 out
__global__ __launch_bounds__(256) void k_reduce4(
    const u16* __restrict__ p0, const u16* __restrict__ p1,
    const u16* __restrict__ p2, const u16* __restrict__ p3,
    const float* __restrict__ X, const float* __restrict__ bias,
    float* __restrict__ out, int n4) {
  int i = blockIdx.x * 256 + threadIdx.x;
  if (i >= n4) return;
  ushort4 a = reinterpret_cast<const ushort4*>(p0)[i];
  ushort4 b = reinterpret_cast<const ushort4*>(p1)[i];
  ushort4 c = reinterpret_cast<const ushort4*>(p2)[i];
  ushort4 d = reinterpret_cast<const ushort4*>(p3)[i];
  float4 xv = reinterpret_cast<const float4*>(X)[i];
  float4 r;
  r.x = xv.x + bf2f(a.x) + bf2f(b.x) + bf2f(c.x) + bf2f(d.x);
  r.y = xv.y + bf2f(a.y) + bf2f(b.y) + bf2f(c.y) + bf2f(d.y);
  r.z = xv.z + bf2f(a.z) + bf2f(b.z) + bf2f(c.z) + bf2f(d.z);
  r.w = xv.w + bf2f(a.w) + bf2f(b.w) + bf2f(c.w) + bf2f(d.w);
  if (bias) {
    int col = (i * 4) & (D_DIM - 1);
    float4 bv = *reinterpret_cast<const float4*>(bias + col);
    r.x += bv.x; r.y += bv.y; r.z += bv.z; r.w += bv.w;
  }
  reinterpret_cast<float4*>(out)[i] = r;
}

// rmsnorm: one block per row of [U_DIM, D_DIM], fp32 in -> bf16 out
__global__ __launch_bounds__(256) void k_rmsnorm(const float* __restrict__ x,
                                                 const float* __restrict__ w,
                                                 u16* __restrict__ out) {
  const int row = blockIdx.x;
  const int t = threadIdx.x;
  const float4* xr = reinterpret_cast<const float4*>(x + (size_t)row * D_DIM);
  float4 a0 = xr[t], a1 = xr[t + 256];
  float ss = a0.x*a0.x + a0.y*a0.y + a0.z*a0.z + a0.w*a0.w
           + a1.x*a1.x + a1.y*a1.y + a1.z*a1.z + a1.w*a1.w;
#pragma unroll
  for (int off = 32; off > 0; off >>= 1) ss += __shfl_xor(ss, off);
  __shared__ float red[4];
  if ((t & 63) == 0) red[t >> 6] = ss;
  __syncthreads();
  float tot = red[0] + red[1] + red[2] + red[3];
  float r = rsqrtf(tot / (float)D_DIM + EPS_RMS);
  const float4* wr = reinterpret_cast<const float4*>(w);
  float4 w0 = wr[t], w1 = wr[t + 256];
  ushort4 o0, o1;
  o0.x = f2bf(a0.x * r * w0.x); o0.y = f2bf(a0.y * r * w0.y);
  o0.z = f2bf(a0.z * r * w0.z); o0.w = f2bf(a0.w * r * w0.w);
  o1.x = f2bf(a1.x * r * w1.x); o1.y = f2bf(a1.y * r * w1.y);
  o1.z = f2bf(a1.z * r * w1.z); o1.w = f2bf(a1.w * r * w1.w);
  ushort4* op = reinterpret_cast<ushort4*>(out + (size_t)row * D_DIM);
  op[t] = o0; op[t + 256] = o1;
}

// ---------------- GEMM core: C[128x128] += A[M,K] * B[N,K]^T ----------------
#define BKD 32

__device__ __forceinline__ void async16(u16* lds, const u16* g) {
  __builtin_amdgcn_global_load_lds(
      (__attribute__((address_space(1))) void*)(g),
      (__attribute__((address_space(3))) void*)(lds), 16, 0, 0);
}

__device__ __forceinline__ void gemm_core(
    const u16* __restrict__ A, int lda,
    const u16* __restrict__ B, int ldb,
    int K, int bm, int bn,
    u16* As, u16* Bs, floatx4 acc[4][4]) {
  const int t = threadIdx.x;
  const int wv = t >> 6, lane = t & 63;
  const int wr = wv >> 1, wc = wv & 1;
  const u16* Ag = A + (size_t)(bm + wv*32 + (lane >> 2)) * lda + (lane & 3) * 8;
  const u16* Bg = B + (size_t)(bn + wv*32 + (lane >> 2)) * ldb + (lane & 3) * 8;
  u16* AsW = As + wv * 1024;
  u16* BsW = Bs + wv * 1024;
  const int fr = lane & 15, kq = lane >> 4;
  const u16* ApF = As + (wr*64 + fr) * BKD + kq * 8;
  const u16* BpF = Bs + (wc*64 + fr) * BKD + kq * 8;
  for (int k0 = 0; k0 < K; k0 += BKD) {
    async16(AsW,       Ag + k0);
    async16(AsW + 512, Ag + (size_t)16*lda + k0);
    async16(BsW,       Bg + k0);
    async16(BsW + 512, Bg + (size_t)16*ldb + k0);
    __syncthreads();
    shortx8 af[4], bf[4];
#pragma unroll
    for (int i = 0; i < 4; i++) af[i] = *reinterpret_cast<const shortx8*>(ApF + i*16*BKD);
#pragma unroll
    for (int i = 0; i < 4; i++) bf[i] = *reinterpret_cast<const shortx8*>(BpF + i*16*BKD);
#pragma unroll
    for (int mi = 0; mi < 4; mi++)
#pragma unroll
      for (int ni = 0; ni < 4; ni++)
        acc[mi][ni] = __builtin_amdgcn_mfma_f32_16x16x32_bf16(af[mi], bf[ni], acc[mi][ni], 0, 0, 0);
    __syncthreads();
  }
}

#define GEMM_PRELUDE                                              \
  __shared__ u16 As[128*BKD], Bs[128*BKD];                        \
  floatx4 acc[4][4];                                              \
  {                                                               \
    floatx4 zf = {0.f, 0.f, 0.f, 0.f};                            \
    for (int i = 0; i < 4; i++)                                   \
      for (int j = 0; j < 4; j++) acc[i][j] = zf;                 \
  }                                                               \
  const int bm = blockIdx.y * 128, bn = blockIdx.x * 128;

#define EPILOG_SETUP                                              \
  const int lane_ = threadIdx.x & 63;                             \
  const int wv_ = threadIdx.x >> 6;                               \
  const int row0 = (wv_ >> 1) * 64 + ((lane_ >> 4) << 2);         \
  const int col0 = (wv_ & 1) * 64 + (lane_ & 15);

// fused QKV: B = [wq; wk; wv] (6144 x 2048). Q,K stored [U,D]; V stored
// transposed as V^T [D, U] (per-head contiguous).
__global__ __launch_bounds__(256) void k_gemm_qkv(
    const u16* __restrict__ A, const u16* __restrict__ B,
    u16* __restrict__ Q, u16* __restrict__ Ko, u16* __restrict__ VT) {
  GEMM_PRELUDE;
  gemm_core(A, D_DIM, B, D_DIM, D_DIM, bm, bn, As, Bs, acc);
  EPILOG_SETUP;
  if (bn < 4096) {  // Q or K, normal store
    u16* C = (bn < 2048) ? Q : Ko;
    const int cb = (bn < 2048) ? bn : bn - 2048;
#pragma unroll
    for (int mt = 0; mt < 4; mt++)
#pragma unroll
      for (int i = 0; i < 4; i++) {
        u16* cr = C + (size_t)(bm + row0 + mt*16 + i) * D_DIM + cb + col0;
#pragma unroll
        for (int nt = 0; nt < 4; nt++) cr[nt*16] = f2bf(acc[mt][nt][i]);
      }
  } else {  // V, transposed store
    const int cb = bn - 4096;
#pragma unroll
    for (int mt = 0; mt < 4; mt++)
#pragma unroll
      for (int nt = 0; nt < 4; nt++) {
        int col = cb + col0 + nt*16;
        int row = bm + row0 + mt*16;
        ushort4 o;
        o.x = f2bf(acc[mt][nt][0]); o.y = f2bf(acc[mt][nt][1]);
        o.z = f2bf(acc[mt][nt][2]); o.w = f2bf(acc[mt][nt][3]);
        *reinterpret_cast<ushort4*>(VT + (size_t)col * U_DIM + row) = o;
      }
  }
}

// ---------------- Flash attention (textbook barriers, 64-key tiles) --------
// Block = (qt, head): 128 Q rows, 32 key-tiles of 64.
// LDS: Ks[64x128] rot16, Vs[128x64] rot8, Pb[128x64] rot8 -> 48 KB.
// Staging: K and V both DMA'd at loop top, fenced by the immediately
// following barrier (exact gemm_core pattern - no mid-phase DMA).
__global__ __launch_bounds__(256) void k_flash(
    const u16* __restrict__ Q, const u16* __restrict__ K,
    const u16* __restrict__ VT, const u16* __restrict__ ADJP,
    u16* __restrict__ O) {
  __shared__ u16 smem[24576];          // 48 KB
  u16* Ks = smem;                      // [64][128] u16
  u16* Vs = smem + 8192;               // [128][64] u16
  u16* Pb = smem + 16384;              // [128][64] u16
  const int qt = blockIdx.x, gh = blockIdx.y;
  const int t = threadIdx.x, wv = t >> 6, lane = t & 63;
  const int fr = lane & 15, kq = lane >> 4;
  const int c8 = lane & 7, r8g = lane >> 3;

  // stage Q tile [128x128] into smem (rot16), extract A-frags
  {
    const u16* gq = Q + (size_t)(qt * 128) * D_DIM + gh * DH;
#pragma unroll
    for (int it = 0; it < 8; it++) {
      int row = wv * 32 + it * 4 + kq;
      int cg = (fr + row) & 15;
      async16(smem + row * 128 + fr * 8, gq + (size_t)row * D_DIM + cg * 8);
    }
  }
  __builtin_amdgcn_s_waitcnt(0);
  __syncthreads();
  shortx8 qf[2][4];
#pragma unroll
  for (int mt = 0; mt < 2; mt++)
#pragma unroll
    for (int ks = 0; ks < 4; ks++) {
      int row = wv * 32 + mt * 16 + fr;
      int slot = ((ks * 4 + kq) - row) & 15;
      qf[mt][ks] = *reinterpret_cast<const shortx8*>(smem + row * 128 + slot * 8);
    }
  __syncthreads();  // done reading Q

  floatx4 oacc[2][8];
  float mrow[2][4], lrow[2][4];
#pragma unroll
  for (int mt = 0; mt < 2; mt++) {
#pragma unroll
    for (int nt = 0; nt < 8; nt++) { floatx4 z = {0.f,0.f,0.f,0.f}; oacc[mt][nt] = z; }
#pragma unroll
    for (int i = 0; i < 4; i++) { mrow[mt][i] = -1e30f; lrow[mt][i] = 0.f; }
  }

  const u16* gk = K + gh * DH;
  const u16* gv = VT + (size_t)(gh * DH) * U_DIM;

  for (int kt = 0; kt < 32; kt++) {
    // stage K tile [64x128] (rot16): wave wv covers rows [wv*16, wv*16+16)
#pragma unroll
    for (int it = 0; it < 4; it++) {
      int row = wv * 16 + it * 4 + kq;
      int cg = (fr + row) & 15;
      async16(Ks + row * 128 + fr * 8,
              gk + (size_t)(kt * 64 + row) * D_DIM + cg * 8);
    }
    // stage V tile [128x64] (rot8): wave wv covers rows [wv*32, wv*32+32)
#pragma unroll
    for (int it = 0; it < 4; it++) {
      int row = wv * 32 + it * 8 + r8g;
      int cg = (c8 + row) & 7;
      async16(Vs + row * 64 + c8 * 8,
              gv + (size_t)row * U_DIM + kt * 64 + cg * 8);
    }
    __builtin_amdgcn_s_waitcnt(0);
    __syncthreads();  // B1: K and V fully in LDS

    // S = Q K^T  (64 keys)
    floatx4 sacc[2][4];
#pragma unroll
    for (int mt = 0; mt < 2; mt++)
#pragma unroll
      for (int nt = 0; nt < 4; nt++) { floatx4 z = {0.f,0.f,0.f,0.f}; sacc[mt][nt] = z; }
#pragma unroll
    for (int ks = 0; ks < 4; ks++) {
      shortx8 kf[4];
#pragma unroll
      for (int nt = 0; nt < 4; nt++) {
        int row = nt * 16 + fr;
        int slot = ((ks * 4 + kq) - row) & 15;
        kf[nt] = *reinterpret_cast<const shortx8*>(Ks + row * 128 + slot * 8);
      }
#pragma unroll
      for (int nt = 0; nt < 4; nt++)
#pragma unroll
        for (int mt = 0; mt < 2; mt++)
          sacc[mt][nt] = __builtin_amdgcn_mfma_f32_16x16x32_bf16(qf[mt][ks], kf[nt], sacc[mt][nt], 0, 0, 0);
    }

    // online softmax (C-layout rows: row = wv*32+mt*16+kq*4+i, col = nt*16+fr)
    const u16* bt = ADJP + (size_t)(qt * 16 + (kt >> 1)) * 16384 + (kt & 1) * 4;
#pragma unroll
    for (int mt = 0; mt < 2; mt++)
#pragma unroll
      for (int i = 0; i < 4; i++) {
        int row = wv * 32 + mt * 16 + kq * 4 + i;
        ushort4 bh4 = *reinterpret_cast<const ushort4*>(bt + ((size_t)fr * 128 + row) * 8);
        float s[4];
        s[0] = sacc[0][0][0];  // placeholder overwritten below
#pragma unroll
        for (int nt = 0; nt < 4; nt++) {
          u16 bu = (nt == 0) ? bh4.x : (nt == 1) ? bh4.y : (nt == 2) ? bh4.z : bh4.w;
          s[nt] = sacc[mt][nt][i] * ATTN_SCALE + h2f(bu);
        }
        float mx = fmaxf(fmaxf(s[0], s[1]), fmaxf(s[2], s[3]));
        mx = fmaxf(mx, __shfl_xor(mx, 1));
        mx = fmaxf(mx, __shfl_xor(mx, 2));
        mx = fmaxf(mx, __shfl_xor(mx, 4));
        mx = fmaxf(mx, __shfl_xor(mx, 8));
        float mnew = fmaxf(mrow[mt][i], mx);
        float alpha = __expf(mrow[mt][i] - mnew);
        mrow[mt][i] = mnew;
        float ps = 0.f;
#pragma unroll
        for (int nt = 0; nt < 4; nt++) {
          float p = __expf(s[nt] - mnew);
          ps += p;
          int col = nt * 16 + fr;
          int slot = ((col >> 3) - row) & 7;
          Pb[row * 64 + slot * 8 + (col & 7)] = f2bf(p);
        }
        ps += __shfl_xor(ps, 1);
        ps += __shfl_xor(ps, 2);
        ps += __shfl_xor(ps, 4);
        ps += __shfl_xor(ps, 8);
        lrow[mt][i] = lrow[mt][i] * alpha + ps;
#pragma unroll
        for (int nt = 0; nt < 8; nt++) oacc[mt][nt][i] *= alpha;
      }
    __syncthreads();  // B2: Pb visible

    // O += P V   (k = 64 -> 2 MFMA k-steps)
#pragma unroll
    for (int ks = 0; ks < 2; ks++) {
      shortx8 vf[8];
#pragma unroll
      for (int nt = 0; nt < 8; nt++) {
        int row = nt * 16 + fr;
        int slot = ((ks * 4 + kq) - row) & 7;
        vf[nt] = *reinterpret_cast<const shortx8*>(Vs + row * 64 + slot * 8);
      }
#pragma unroll
      for (int mt = 0; mt < 2; mt++) {
        int row = wv * 32 + mt * 16 + fr;
        int slot = ((ks * 4 + kq) - row) & 7;
        shortx8 pf = *reinterpret_cast<const shortx8*>(Pb + row * 64 + slot * 8);
#pragma unroll
        for (int nt = 0; nt < 8; nt++)
          oacc[mt][nt] = __builtin_amdgcn_mfma_f32_16x16x32_bf16(pf, vf[nt], oacc[mt][nt], 0, 0, 0);
      }
    }
    __syncthreads();  // B3: Ks/Vs/Pb free for next iteration
  }

  // epilogue: normalize by l, store bf16 to O[U, D] at head col block
#pragma unroll
  for (int mt = 0; mt < 2; mt++)
#pragma unroll
    for (int i = 0; i < 4; i++) {
      int row = wv * 32 + mt * 16 + kq * 4 + i;
      float inv = 1.f / lrow[mt][i];
      u16* orow = O + (size_t)(qt * 128 + row) * D_DIM + gh * DH + fr;
#pragma unroll
      for (int nt = 0; nt < 8; nt++)
        orow[nt * 16] = f2bf(oacc[mt][nt][i] * inv);
    }
}

// split-K GEMM into 4 bf16 partial buffers (grid.z = split)
__global__ __launch_bounds__(256) void k_gemm_splitk_part(
    const u16* __restrict__ A, int lda, const u16* __restrict__ B, int ldb,
    int Kc, u16* __restrict__ P, size_t pstride, int ldc) {
  GEMM_PRELUDE;
  const int koff = blockIdx.z * Kc;
  gemm_core(A + koff, lda, B + koff, ldb, Kc, bm, bn, As, Bs, acc);
  u16* Pz = P + (size_t)blockIdx.z * pstride;
  EPILOG_SETUP;
#pragma unroll
  for (int mt = 0; mt < 4; mt++)
#pragma unroll
    for (int i = 0; i < 4; i++) {
      u16* cr = Pz + (size_t)(bm + row0 + mt*16 + i) * ldc + bn + col0;
#pragma unroll
      for (int nt = 0; nt < 4; nt++) cr[nt*16] = f2bf(acc[mt][nt][i]);
    }
}

// fast gelu: tanh form via exp (abs err ~1e-3, well under threshold)
__device__ __forceinline__ float fast_gelu(float v) {
  float u = v * (0.79788456080286536f + 0.035677408136300125f * v * v);
  float tt = fminf(fmaxf(2.f * u, -40.f), 40.f);
  float e = __expf(tt);
  return 0.5f * v * (1.f + (e - 1.f) / (e + 1.f));
}

// gelu(A@B^T + bias) -> bf16
__global__ __launch_bounds__(256) void k_gemm_gelu(
    const u16* __restrict__ A, int lda, const u16* __restrict__ B, int ldb,
    int K, const float* __restrict__ bias, u16* __restrict__ C, int ldc) {
  GEMM_PRELUDE;
  gemm_core(A, lda, B, ldb, K, bm, bn, As, Bs, acc);
  EPILOG_SETUP;
#pragma unroll
  for (int mt = 0; mt < 4; mt++)
#pragma unroll
    for (int i = 0; i < 4; i++) {
      size_t off = (size_t)(bm + row0 + mt*16 + i) * ldc + bn + col0;
#pragma unroll
      for (int nt = 0; nt < 4; nt++) {
        float v = acc[mt][nt][i] + bias[bn + col0 + nt*16];
        C[off + nt*16] = f2bf(fast_gelu(v));
      }
    }
}

// Workspace timeline (MB offsets, peak 104):
//  A: hb@0-8, wob@48-56, wqkv@56-80, adjp@32-40 (prep)
//  B: qkv -> qb@8-16 kb@16-24 vtb@24-32
//  C: flash -> aob@40-48  (reads qb,kb,vtb,adjp)
//  D: out-proj partials opp@8-40 (qb/kb/vtb/adjp dead); reduce -> out = x + sum
//  E: h2b@0-8, wub@8-40 (opp dead), ffb@40-72 (aob/wob/wqkv dead), wdb@72-104,
//     down partials dpp@8-40 (wub dead after gelu); reduce -> out += sum + b_down
extern "C" void kernel_launch(void* const* d_in, const int* in_sizes, int n_in,
                              void* d_out, int out_size, void* d_ws, size_t ws_size,
                              hipStream_t stream) {
  (void)in_sizes; (void)n_in; (void)out_size; (void)ws_size;
  const float* x      = (const float*)d_in[0];
  const float* adj    = (const float*)d_in[1];
  const float* n1w    = (const float*)d_in[2];
  const float* n2w    = (const float*)d_in[3];
  const float* wq     = (const float*)d_in[4];
  const float* wk     = (const float*)d_in[5];
  const float* wv     = (const float*)d_in[6];
  const float* wo     = (const float*)d_in[7];
  const float* w_up   = (const float*)d_in[8];
  const float* b_up   = (const float*)d_in[9];
  const float* w_down = (const float*)d_in[10];
  const float* b_down = (const float*)d_in[11];
  float* out = (float*)d_out;
  char* ws = (char*)d_ws;
  const size_t MB = 1u << 20;
  u16* hb   = (u16*)(ws + 0*MB);
  u16* qb   = (u16*)(ws + 8*MB);
  u16* kb   = (u16*)(ws + 16*MB);
  u16* vtb  = (u16*)(ws + 24*MB);
  u16* adjp = (u16*)(ws + 32*MB);
  u16* aob  = (u16*)(ws + 40*MB);
  u16* wob  = (u16*)(ws + 48*MB);
  u16* wqkv = (u16*)(ws + 56*MB);
  u16* opp  = (u16*)(ws + 8*MB);   // 4 x 8MB out-proj partials
  u16* h2b  = (u16*)(ws + 0*MB);
  u16* wub  = (u16*)(ws + 8*MB);
  u16* ffb  = (u16*)(ws + 40*MB);
  u16* wdb  = (u16*)(ws + 72*MB);
  u16* dpp  = (u16*)(ws + 8*MB);   // 4 x 8MB FFN-down partials (overlays wub)

  dim3 blk(256);
  const int n4d = (D_DIM * D_DIM) / 4;
  const int n4f = (DFF * D_DIM) / 4;
  const size_t szd = (size_t)D_DIM * D_DIM;

  // phase A: weight conversion + bias permute + norm1
  k_f2b<<<(n4d + 255) / 256, blk, 0, stream>>>(wq, wqkv, n4d);
  k_f2b<<<(n4d + 255) / 256, blk, 0, stream>>>(wk, wqkv + szd, n4d);
  k_f2b<<<(n4d + 255) / 256, blk, 0, stream>>>(wv, wqkv + 2*szd, n4d);
  k_f2b<<<(n4d + 255) / 256, blk, 0, stream>>>(wo, wob, n4d);
  k_prep_bias<<<256, blk, 0, stream>>>(adj, adjp);
  k_rmsnorm<<<U_DIM, blk, 0, stream>>>(x, n1w, hb);

  // phase B: fused QKV (768 blocks)
  k_gemm_qkv<<<dim3(48, 16), blk, 0, stream>>>(hb, wqkv, qb, kb, vtb);

  // phase C: flash attention (256 blocks) -> aob
  k_flash<<<dim3(16, 16), blk, 0, stream>>>(qb, kb, vtb, adjp, aob);

  // phase D: out-projection split-K4 -> partials; reduce adds residual x
  k_gemm_splitk_part<<<dim3(16, 16, 4), blk, 0, stream>>>(
      aob, D_DIM, wob, D_DIM, D_DIM/4, opp, szd, D_DIM);
  k_reduce4<<<(n4d + 255) / 256, blk, 0, stream>>>(
      opp, opp + szd, opp + 2*szd, opp + 3*szd, x, nullptr, out, n4d);

  // phase E: FFN
  k_rmsnorm<<<U_DIM, blk, 0, stream>>>(out, n2w, h2b);
  k_f2b<<<(n4f + 255) / 256, blk, 0, stream>>>(w_up, wub, n4f);
  k_gemm_gelu<<<dim3(64, 16), blk, 0, stream>>>(h2b, D_DIM, wub, D_DIM, D_DIM,
                                                b_up, ffb, DFF);
  k_f2b<<<(n4f + 255) / 256, blk, 0, stream>>>(w_down, wdb, n4f);
  k_gemm_splitk_part<<<dim3(16, 16, 4), blk, 0, stream>>>(
      ffb, DFF, wdb, DFF, DFF/4, dpp, szd, D_DIM);
  k_reduce4<<<(n4d + 255) / 256, blk, 0, stream>>>(
      dpp, dpp + szd, dpp + 2*szd, dpp + 3*szd, out, b_down, out, n4d);
}

// Round 6
// 739.175 us; speedup vs baseline: 1.3907x; 1.0237x over previous
//
#include <hip/hip_runtime.h>
#include <hip/hip_fp16.h>
#include <cstdint>
#include <cstddef>

#define U_DIM 2048
#define D_DIM 2048
#define NH 16
#define DH 128
#define DFF 8192
#define EPS_RMS 1e-6f
#define ATTN_SCALE 0.088388347648318447f

typedef unsigned short u16;
typedef __attribute__((ext_vector_type(4))) float floatx4;
typedef __attribute__((ext_vector_type(8))) short shortx8;

__device__ __forceinline__ float bf2f(u16 u) {
  union { unsigned int i; float f; } v; v.i = ((unsigned int)u) << 16; return v.f;
}
__device__ __forceinline__ u16 f2bf(float f) {
  union { float f; unsigned int i; } v; v.f = f;
  return (u16)((v.i + 0x7fffu + ((v.i >> 16) & 1u)) >> 16);
}
__device__ __forceinline__ u16 f2h(float f) {
  __half h = __float2half_rn(f);
  union { __half h; u16 u; } c; c.h = h; return c.u;
}
__device__ __forceinline__ float h2f(u16 u) {
  union { __half h; u16 u; } c; c.u = u; return __half2float(c.h);
}

// fp32 -> bf16 bulk convert (n4 = n/4 float4 groups)
__global__ __launch_bounds__(256) void k_f2b(const float* __restrict__ in,
                                             u16* __restrict__ out, int n4) {
  int i = blockIdx.x * 256 + threadIdx.x;
  if (i >= n4) return;
  float4 f = reinterpret_cast<const float4*>(in)[i];
  ushort4 o;
  o.x = f2bf(f.x); o.y = f2bf(f.y); o.z = f2bf(f.z); o.w = f2bf(f.w);
  reinterpret_cast<ushort4*>(out)[i] = o;
}

// Permute adj fp32 [U,U] into frag-major fp16 tiles:
// adjp[(qt*16+kt)*16384 + (c16*128 + row)*8 + j] = adj[qt*128+row][kt*128+c16+16*j]
__global__ __launch_bounds__(256) void k_prep_bias(const float* __restrict__ adj,
                                                   u16* __restrict__ adjp) {
  const int tile = blockIdx.x;           // qt*16 + kt
  const int qt = tile >> 4, kt = tile & 15;
  const int t = threadIdx.x;
  const int c16 = t & 15, rblk = t >> 4; // 16 row-groups of 8
  u16* outt = adjp + (size_t)tile * 16384;
#pragma unroll
  for (int rr = 0; rr < 8; rr++) {
    int r = rblk * 8 + rr;
    const float* src = adj + (size_t)(qt * 128 + r) * U_DIM + kt * 128 + c16;
    ushort4 o0, o1;
    o0.x = f2h(src[0]);    o0.y = f2h(src[16]);  o0.z = f2h(src[32]);  o0.w = f2h(src[48]);
    o1.x = f2h(src[64]);   o1.y = f2h(src[80]);  o1.z = f2h(src[96]);  o1.w = f2h(src[112]);
    ushort4* dst = reinterpret_cast<ushort4*>(outt + ((size_t)c16 * 128 + r) * 8);
    dst[0] = o0; dst[1] = o1;
  }
}

// out4 = X4 + sum of 4 bf16 partials (+ bias[col]); fp32 out
__global__ __launch_bounds__(256) void k_reduce4(
    const u16* __restrict__ p0, const u16* __restrict__ p1,
    const u16* __restrict__ p2, const u16* __restrict__ p3,
    const float* __restrict__ X, const float* __restrict__ bias,
    float* __restrict__ out, int n4) {
  int i = blockIdx.x * 256 + threadIdx.x;
  if (i >= n4) return;
  ushort4 a = reinterpret_cast<const ushort4*>(p0)[i];
  ushort4 b = reinterpret_cast<const ushort4*>(p1)[i];
  ushort4 c = reinterpret_cast<const ushort4*>(p2)[i];
  ushort4 d = reinterpret_cast<const ushort4*>(p3)[i];
  float4 xv = reinterpret_cast<const float4*>(X)[i];
  float4 r;
  r.x = xv.x + bf2f(a.x) + bf2f(b.x) + bf2f(c.x) + bf2f(d.x);
  r.y = xv.y + bf2f(a.y) + bf2f(b.y) + bf2f(c.y) + bf2f(d.y);
  r.z = xv.z + bf2f(a.z) + bf2f(b.z) + bf2f(c.z) + bf2f(d.z);
  r.w = xv.w + bf2f(a.w) + bf2f(b.w) + bf2f(c.w) + bf2f(d.w);
  if (bias) {
    int col = (i * 4) & (D_DIM - 1);
    float4 bv = *reinterpret_cast<const float4*>(bias + col);
    r.x += bv.x; r.y += bv.y; r.z += bv.z; r.w += bv.w;
  }
  reinterpret_cast<float4*>(out)[i] = r;
}

// rmsnorm: one block per row of [U_DIM, D_DIM], fp32 in -> bf16 out
__global__ __launch_bounds__(256) void k_rmsnorm(const float* __restrict__ x,
                                                 const float* __restrict__ w,
                                                 u16* __restrict__ out) {
  const int row = blockIdx.x;
  const int t = threadIdx.x;
  const float4* xr = reinterpret_cast<const float4*>(x + (size_t)row * D_DIM);
  float4 a0 = xr[t], a1 = xr[t + 256];
  float ss = a0.x*a0.x + a0.y*a0.y + a0.z*a0.z + a0.w*a0.w
           + a1.x*a1.x + a1.y*a1.y + a1.z*a1.z + a1.w*a1.w;
#pragma unroll
  for (int off = 32; off > 0; off >>= 1) ss += __shfl_xor(ss, off);
  __shared__ float red[4];
  if ((t & 63) == 0) red[t >> 6] = ss;
  __syncthreads();
  float tot = red[0] + red[1] + red[2] + red[3];
  float r = rsqrtf(tot / (float)D_DIM + EPS_RMS);
  const float4* wr = reinterpret_cast<const float4*>(w);
  float4 w0 = wr[t], w1 = wr[t + 256];
  ushort4 o0, o1;
  o0.x = f2bf(a0.x * r * w0.x); o0.y = f2bf(a0.y * r * w0.y);
  o0.z = f2bf(a0.z * r * w0.z); o0.w = f2bf(a0.w * r * w0.w);
  o1.x = f2bf(a1.x * r * w1.x); o1.y = f2bf(a1.y * r * w1.y);
  o1.z = f2bf(a1.z * r * w1.z); o1.w = f2bf(a1.w * r * w1.w);
  ushort4* op = reinterpret_cast<ushort4*>(out + (size_t)row * D_DIM);
  op[t] = o0; op[t + 256] = o1;
}

// ---------------- GEMM core: C[128x128] += A[M,K] * B[N,K]^T ----------------
#define BKD 32

__device__ __forceinline__ void async16(u16* lds, const u16* g) {
  __builtin_amdgcn_global_load_lds(
      (__attribute__((address_space(1))) void*)(g),
      (__attribute__((address_space(3))) void*)(lds), 16, 0, 0);
}

__device__ __forceinline__ void gemm_core(
    const u16* __restrict__ A, int lda,
    const u16* __restrict__ B, int ldb,
    int K, int bm, int bn,
    u16* As, u16* Bs, floatx4 acc[4][4]) {
  const int t = threadIdx.x;
  const int wv = t >> 6, lane = t & 63;
  const int wr = wv >> 1, wc = wv & 1;
  const u16* Ag = A + (size_t)(bm + wv*32 + (lane >> 2)) * lda + (lane & 3) * 8;
  const u16* Bg = B + (size_t)(bn + wv*32 + (lane >> 2)) * ldb + (lane & 3) * 8;
  u16* AsW = As + wv * 1024;
  u16* BsW = Bs + wv * 1024;
  const int fr = lane & 15, kq = lane >> 4;
  const u16* ApF = As + (wr*64 + fr) * BKD + kq * 8;
  const u16* BpF = Bs + (wc*64 + fr) * BKD + kq * 8;
  for (int k0 = 0; k0 < K; k0 += BKD) {
    async16(AsW,       Ag + k0);
    async16(AsW + 512, Ag + (size_t)16*lda + k0);
    async16(BsW,       Bg + k0);
    async16(BsW + 512, Bg + (size_t)16*ldb + k0);
    __syncthreads();
    shortx8 af[4], bf[4];
#pragma unroll
    for (int i = 0; i < 4; i++) af[i] = *reinterpret_cast<const shortx8*>(ApF + i*16*BKD);
#pragma unroll
    for (int i = 0; i < 4; i++) bf[i] = *reinterpret_cast<const shortx8*>(BpF + i*16*BKD);
#pragma unroll
    for (int mi = 0; mi < 4; mi++)
#pragma unroll
      for (int ni = 0; ni < 4; ni++)
        acc[mi][ni] = __builtin_amdgcn_mfma_f32_16x16x32_bf16(af[mi], bf[ni], acc[mi][ni], 0, 0, 0);
    __syncthreads();
  }
}

#define GEMM_PRELUDE                                              \
  __shared__ u16 As[128*BKD], Bs[128*BKD];                        \
  floatx4 acc[4][4];                                              \
  {                                                               \
    floatx4 zf = {0.f, 0.f, 0.f, 0.f};                            \
    for (int i = 0; i < 4; i++)                                   \
      for (int j = 0; j < 4; j++) acc[i][j] = zf;                 \
  }                                                               \
  const int bm = blockIdx.y * 128, bn = blockIdx.x * 128;

#define EPILOG_SETUP                                              \
  const int lane_ = threadIdx.x & 63;                             \
  const int wv_ = threadIdx.x >> 6;                               \
  const int row0 = (wv_ >> 1) * 64 + ((lane_ >> 4) << 2);         \
  const int col0 = (wv_ & 1) * 64 + (lane_ & 15);

// fused QKV: B = [wq; wk; wv] (6144 x 2048). Q,K stored [U,D]; V stored
// transposed as V^T [D, U] (per-head contiguous).
__global__ __launch_bounds__(256) void k_gemm_qkv(
    const u16* __restrict__ A, const u16* __restrict__ B,
    u16* __restrict__ Q, u16* __restrict__ Ko, u16* __restrict__ VT) {
  GEMM_PRELUDE;
  gemm_core(A, D_DIM, B, D_DIM, D_DIM, bm, bn, As, Bs, acc);
  EPILOG_SETUP;
  if (bn < 4096) {  // Q or K, normal store
    u16* C = (bn < 2048) ? Q : Ko;
    const int cb = (bn < 2048) ? bn : bn - 2048;
#pragma unroll
    for (int mt = 0; mt < 4; mt++)
#pragma unroll
      for (int i = 0; i < 4; i++) {
        u16* cr = C + (size_t)(bm + row0 + mt*16 + i) * D_DIM + cb + col0;
#pragma unroll
        for (int nt = 0; nt < 4; nt++) cr[nt*16] = f2bf(acc[mt][nt][i]);
      }
  } else {  // V, transposed store
    const int cb = bn - 4096;
#pragma unroll
    for (int mt = 0; mt < 4; mt++)
#pragma unroll
      for (int nt = 0; nt < 4; nt++) {
        int col = cb + col0 + nt*16;
        int row = bm + row0 + mt*16;
        ushort4 o;
        o.x = f2bf(acc[mt][nt][0]); o.y = f2bf(acc[mt][nt][1]);
        o.z = f2bf(acc[mt][nt][2]); o.w = f2bf(acc[mt][nt][3]);
        *reinterpret_cast<ushort4*>(VT + (size_t)col * U_DIM + row) = o;
      }
  }
}

// ---------------- Flash attention v2: 64-row Q tiles, 32-key tiles, --------
// double-buffered K/V with prefetch-at-top.  Grid (32, 16) = 512 blocks
// = 2 resident blocks/CU.  LDS 36 KB:
//   Ks[2]: [32][128] @0/@4096, Vs[2]: [128][32] @8192/@12288, Pb: [64][32] @16384
// Sync: B1 = explicit s_waitcnt(0)+barrier (drains the prefetch DMAs issued
// one iteration earlier).  B2/B3 = plain __syncthreads (LDS fencing only; the
// in-flight prefetch DMA is NOT drained there - verified round-4/5 behavior).
__global__ __launch_bounds__(256) void k_flash(
    const u16* __restrict__ Q, const u16* __restrict__ K,
    const u16* __restrict__ VT, const u16* __restrict__ ADJP,
    u16* __restrict__ O) {
  __shared__ u16 smem[18432];  // 36 KB
  const int qt = blockIdx.x, gh = blockIdx.y;   // qt in [0,32)
  const int t = threadIdx.x, wv = t >> 6, lane = t & 63;
  const int fr = lane & 15, kq = lane >> 4;
  const int c4 = lane & 3, r4 = lane >> 2;

  const u16* gq = Q + (size_t)(qt * 64) * D_DIM + gh * DH;
  const u16* gk = K + gh * DH;
  const u16* gv = VT + (size_t)(gh * DH) * U_DIM;

  // stage Q [64][128] rot16 into smem[0..8192)
#pragma unroll
  for (int it = 0; it < 4; it++) {
    int row = wv * 16 + it * 4 + kq;
    int cg = (fr + row) & 15;
    async16(smem + row * 128 + fr * 8, gq + (size_t)row * D_DIM + cg * 8);
  }
  __builtin_amdgcn_s_waitcnt(0);
  __syncthreads();
  shortx8 qf[4];
#pragma unroll
  for (int ks = 0; ks < 4; ks++) {
    int row = wv * 16 + fr;
    int slot = ((ks * 4 + kq) - row) & 15;
    qf[ks] = *reinterpret_cast<const shortx8*>(smem + row * 128 + slot * 8);
  }
  __syncthreads();  // Q reads done; smem reusable

  floatx4 oacc[8];
  float mrow[4], lrow[4];
#pragma unroll
  for (int nt = 0; nt < 8; nt++) { floatx4 z = {0.f,0.f,0.f,0.f}; oacc[nt] = z; }
#pragma unroll
  for (int i = 0; i < 4; i++) { mrow[i] = -1e30f; lrow[i] = 0.f; }

  // stage K/V tile 0 into buffer 0
  {
    u16* Ks = smem; u16* Vs = smem + 8192;
#pragma unroll
    for (int it = 0; it < 2; it++) {
      int row = wv * 8 + it * 4 + kq;
      int cg = (fr + row) & 15;
      async16(Ks + row * 128 + fr * 8, gk + (size_t)row * D_DIM + cg * 8);
    }
#pragma unroll
    for (int it = 0; it < 2; it++) {
      int row = wv * 32 + it * 16 + r4;
      int cg = (c4 + (row >> 1)) & 3;
      async16(Vs + row * 32 + c4 * 8, gv + (size_t)row * U_DIM + cg * 8);
    }
  }

  u16* Pb = smem + 16384;
  for (int kt = 0; kt < 64; kt++) {
    const int cur = kt & 1;
    u16* Ks = smem + cur * 4096;
    u16* Vs = smem + 8192 + cur * 4096;
    __builtin_amdgcn_s_waitcnt(0);
    __syncthreads();  // B1: buf[cur] DMA complete, all waves arrived
    if (kt < 63) {    // prefetch buf[1-cur] for kt+1; flies through compute
      u16* Kn = smem + (1 - cur) * 4096;
      u16* Vn = smem + 8192 + (1 - cur) * 4096;
      const u16* gkn = gk + (size_t)((kt + 1) * 32) * D_DIM;
      const u16* gvn = gv + (kt + 1) * 32;
#pragma unroll
      for (int it = 0; it < 2; it++) {
        int row = wv * 8 + it * 4 + kq;
        int cg = (fr + row) & 15;
        async16(Kn + row * 128 + fr * 8, gkn + (size_t)row * D_DIM + cg * 8);
      }
#pragma unroll
      for (int it = 0; it < 2; it++) {
        int row = wv * 32 + it * 16 + r4;
        int cg = (c4 + (row >> 1)) & 3;
        async16(Vn + row * 32 + c4 * 8, gvn + (size_t)row * U_DIM + cg * 8);
      }
    }

    // S = Q K^T (32 keys)
    floatx4 sacc[2];
    { floatx4 z = {0.f,0.f,0.f,0.f}; sacc[0] = z; sacc[1] = z; }
#pragma unroll
    for (int ks = 0; ks < 4; ks++) {
      int slot0 = ((ks * 4 + kq) - fr) & 15;
      shortx8 kf0 = *reinterpret_cast<const shortx8*>(Ks + fr * 128 + slot0 * 8);
      int slot1 = ((ks * 4 + kq) - (16 + fr)) & 15;
      shortx8 kf1 = *reinterpret_cast<const shortx8*>(Ks + (16 + fr) * 128 + slot1 * 8);
      sacc[0] = __builtin_amdgcn_mfma_f32_16x16x32_bf16(qf[ks], kf0, sacc[0], 0, 0, 0);
      sacc[1] = __builtin_amdgcn_mfma_f32_16x16x32_bf16(qf[ks], kf1, sacc[1], 0, 0, 0);
    }

    // online softmax (C-layout: row = wv*16 + kq*4 + i, col = nt*16 + fr)
    const u16* bt = ADJP + ((size_t)(qt >> 1) * 16 + (kt >> 2)) * 16384 + (kt & 3) * 2;
#pragma unroll
    for (int i = 0; i < 4; i++) {
      int rl = wv * 16 + kq * 4 + i;
      int r128 = (qt & 1) * 64 + rl;
      ushort2 bh = *reinterpret_cast<const ushort2*>(bt + ((size_t)fr * 128 + r128) * 8);
      float s0 = sacc[0][i] * ATTN_SCALE + h2f(bh.x);
      float s1 = sacc[1][i] * ATTN_SCALE + h2f(bh.y);
      float mx = fmaxf(s0, s1);
      mx = fmaxf(mx, __shfl_xor(mx, 1));
      mx = fmaxf(mx, __shfl_xor(mx, 2));
      mx = fmaxf(mx, __shfl_xor(mx, 4));
      mx = fmaxf(mx, __shfl_xor(mx, 8));
      float mnew = fmaxf(mrow[i], mx);
      float alpha = __expf(mrow[i] - mnew);
      mrow[i] = mnew;
      float p0 = __expf(s0 - mnew), p1 = __expf(s1 - mnew);
      int slot0 = ((fr >> 3) - (rl >> 1)) & 3;
      Pb[rl * 32 + slot0 * 8 + (fr & 7)] = f2bf(p0);
      int slot1 = (((16 + fr) >> 3) - (rl >> 1)) & 3;
      Pb[rl * 32 + slot1 * 8 + (fr & 7)] = f2bf(p1);
      float ps = p0 + p1;
      ps += __shfl_xor(ps, 1);
      ps += __shfl_xor(ps, 2);
      ps += __shfl_xor(ps, 4);
      ps += __shfl_xor(ps, 8);
      lrow[i] = lrow[i] * alpha + ps;
#pragma unroll
      for (int nt = 0; nt < 8; nt++) oacc[nt][i] *= alpha;
    }
    __syncthreads();  // B2: Pb visible (lgkm only; prefetch stays in flight)

    // O += P V   (k = 32 -> one MFMA k-step)
    shortx8 pf;
    {
      int row = wv * 16 + fr;
      int slot = (kq - (row >> 1)) & 3;
      pf = *reinterpret_cast<const shortx8*>(Pb + row * 32 + slot * 8);
    }
#pragma unroll
    for (int nt = 0; nt < 8; nt++) {
      int row = nt * 16 + fr;
      int slot = (kq - (row >> 1)) & 3;
      shortx8 vf = *reinterpret_cast<const shortx8*>(Vs + row * 32 + slot * 8);
      oacc[nt] = __builtin_amdgcn_mfma_f32_16x16x32_bf16(pf, vf, oacc[nt], 0, 0, 0);
    }
    __syncthreads();  // B3: Pb/Vs reads retired before next-iter writes
  }

  // epilogue: normalize by l, store bf16 to O[U, D] at head col block
#pragma unroll
  for (int i = 0; i < 4; i++) {
    int rl = wv * 16 + kq * 4 + i;
    float inv = 1.f / lrow[i];
    u16* orow = O + (size_t)(qt * 64 + rl) * D_DIM + gh * DH + fr;
#pragma unroll
    for (int nt = 0; nt < 8; nt++)
      orow[nt * 16] = f2bf(oacc[nt][i] * inv);
  }
}

// split-K GEMM into 4 bf16 partial buffers (grid.z = split)
__global__ __launch_bounds__(256) void k_gemm_splitk_part(
    const u16* __restrict__ A, int lda, const u16* __restrict__ B, int ldb,
    int Kc, u16* __restrict__ P, size_t pstride, int ldc) {
  GEMM_PRELUDE;
  const int koff = blockIdx.z * Kc;
  gemm_core(A + koff, lda, B + koff, ldb, Kc, bm, bn, As, Bs, acc);
  u16* Pz = P + (size_t)blockIdx.z * pstride;
  EPILOG_SETUP;
#pragma unroll
  for (int mt = 0; mt < 4; mt++)
#pragma unroll
    for (int i = 0; i < 4; i++) {
      u16* cr = Pz + (size_t)(bm + row0 + mt*16 + i) * ldc + bn + col0;
#pragma unroll
      for (int nt = 0; nt < 4; nt++) cr[nt*16] = f2bf(acc[mt][nt][i]);
    }
}

// fast gelu: tanh form via exp (abs err ~1e-3, well under threshold)
__device__ __forceinline__ float fast_gelu(float v) {
  float u = v * (0.79788456080286536f + 0.035677408136300125f * v * v);
  float tt = fminf(fmaxf(2.f * u, -40.f), 40.f);
  float e = __expf(tt);
  return 0.5f * v * (1.f + (e - 1.f) / (e + 1.f));
}

// gelu(A@B^T + bias) -> bf16
__global__ __launch_bounds__(256) void k_gemm_gelu(
    const u16* __restrict__ A, int lda, const u16* __restrict__ B, int ldb,
    int K, const float* __restrict__ bias, u16* __restrict__ C, int ldc) {
  GEMM_PRELUDE;
  gemm_core(A, lda, B, ldb, K, bm, bn, As, Bs, acc);
  EPILOG_SETUP;
#pragma unroll
  for (int mt = 0; mt < 4; mt++)
#pragma unroll
    for (int i = 0; i < 4; i++) {
      size_t off = (size_t)(bm + row0 + mt*16 + i) * ldc + bn + col0;
#pragma unroll
      for (int nt = 0; nt < 4; nt++) {
        float v = acc[mt][nt][i] + bias[bn + col0 + nt*16];
        C[off + nt*16] = f2bf(fast_gelu(v));
      }
    }
}

// Workspace timeline (MB offsets, peak 104):
//  A: hb@0-8, wob@48-56, wqkv@56-80, adjp@32-40 (prep)
//  B: qkv -> qb@8-16 kb@16-24 vtb@24-32
//  C: flash -> aob@40-48  (reads qb,kb,vtb,adjp)
//  D: out-proj partials opp@8-40 (qb/kb/vtb/adjp dead); reduce -> out = x + sum
//  E: h2b@0-8, wub@8-40 (opp dead), ffb@40-72 (aob/wob/wqkv dead), wdb@72-104,
//     down partials dpp@8-40 (wub dead after gelu); reduce -> out += sum + b_down
extern "C" void kernel_launch(void* const* d_in, const int* in_sizes, int n_in,
                              void* d_out, int out_size, void* d_ws, size_t ws_size,
                              hipStream_t stream) {
  (void)in_sizes; (void)n_in; (void)out_size; (void)ws_size;
  const float* x      = (const float*)d_in[0];
  const float* adj    = (const float*)d_in[1];
  const float* n1w    = (const float*)d_in[2];
  const float* n2w    = (const float*)d_in[3];
  const float* wq     = (const float*)d_in[4];
  const float* wk     = (const float*)d_in[5];
  const float* wv     = (const float*)d_in[6];
  const float* wo     = (const float*)d_in[7];
  const float* w_up   = (const float*)d_in[8];
  const float* b_up   = (const float*)d_in[9];
  const float* w_down = (const float*)d_in[10];
  const float* b_down = (const float*)d_in[11];
  float* out = (float*)d_out;
  char* ws = (char*)d_ws;
  const size_t MB = 1u << 20;
  u16* hb   = (u16*)(ws + 0*MB);
  u16* qb   = (u16*)(ws + 8*MB);
  u16* kb   = (u16*)(ws + 16*MB);
  u16* vtb  = (u16*)(ws + 24*MB);
  u16* adjp = (u16*)(ws + 32*MB);
  u16* aob  = (u16*)(ws + 40*MB);
  u16* wob  = (u16*)(ws + 48*MB);
  u16* wqkv = (u16*)(ws + 56*MB);
  u16* opp  = (u16*)(ws + 8*MB);   // 4 x 8MB out-proj partials
  u16* h2b  = (u16*)(ws + 0*MB);
  u16* wub  = (u16*)(ws + 8*MB);
  u16* ffb  = (u16*)(ws + 40*MB);
  u16* wdb  = (u16*)(ws + 72*MB);
  u16* dpp  = (u16*)(ws + 8*MB);   // 4 x 8MB FFN-down partials (overlays wub)

  dim3 blk(256);
  const int n4d = (D_DIM * D_DIM) / 4;
  const int n4f = (DFF * D_DIM) / 4;
  const size_t szd = (size_t)D_DIM * D_DIM;

  // phase A: weight conversion + bias permute + norm1
  k_f2b<<<(n4d + 255) / 256, blk, 0, stream>>>(wq, wqkv, n4d);
  k_f2b<<<(n4d + 255) / 256, blk, 0, stream>>>(wk, wqkv + szd, n4d);
  k_f2b<<<(n4d + 255) / 256, blk, 0, stream>>>(wv, wqkv + 2*szd, n4d);
  k_f2b<<<(n4d + 255) / 256, blk, 0, stream>>>(wo, wob, n4d);
  k_prep_bias<<<256, blk, 0, stream>>>(adj, adjp);
  k_rmsnorm<<<U_DIM, blk, 0, stream>>>(x, n1w, hb);

  // phase B: fused QKV (768 blocks)
  k_gemm_qkv<<<dim3(48, 16), blk, 0, stream>>>(hb, wqkv, qb, kb, vtb);

  // phase C: flash attention (512 blocks, 2/CU) -> aob
  k_flash<<<dim3(32, 16), blk, 0, stream>>>(qb, kb, vtb, adjp, aob);

  // phase D: out-projection split-K4 -> partials; reduce adds residual x
  k_gemm_splitk_part<<<dim3(16, 16, 4), blk, 0, stream>>>(
      aob, D_DIM, wob, D_DIM, D_DIM/4, opp, szd, D_DIM);
  k_reduce4<<<(n4d + 255) / 256, blk, 0, stream>>>(
      opp, opp + szd, opp + 2*szd, opp + 3*szd, x, nullptr, out, n4d);

  // phase E: FFN
  k_rmsnorm<<<U_DIM, blk, 0, stream>>>(out, n2w, h2b);
  k_f2b<<<(n4f + 255) / 256, blk, 0, stream>>>(w_up, wub, n4f);
  k_gemm_gelu<<<dim3(64, 16), blk, 0, stream>>>(h2b, D_DIM, wub, D_DIM, D_DIM,
                                                b_up, ffb, DFF);
  k_f2b<<<(n4f + 255) / 256, blk, 0, stream>>>(w_down, wdb, n4f);
  k_gemm_splitk_part<<<dim3(16, 16, 4), blk, 0, stream>>>(
      ffb, DFF, wdb, DFF, DFF/4, dpp, szd, D_DIM);
  k_reduce4<<<(n4d + 255) / 256, blk, 0, stream>>>(
      dpp, dpp + szd, dpp + 2*szd, dpp + 3*szd, out, b_down, out, n4d);
}